// Round 15
// baseline (167.865 us; speedup 1.0000x reference)
//
#include <hip/hip_runtime.h>
#include <hip/hip_bf16.h>
#include <math.h>

#define N_NODES 50000
#define N_EDGES 800000
#define BB 2
#define WFEAT 128
#define DD 64
#define OUTD 128
#define NROWS (BB * N_NODES)      // 100000
#define SCAN_B 256
#define NBLK ((N_NODES + SCAN_B - 1) / SCAN_B)   // 196

#define PROJ_TB ((N_NODES + 127) / 128)          // 391
#define CVTX_B 6250               // NROWS*WFEAT/8/256
#define CVTW_B 16                 // OUTD*256/8/256
#define HIST_B 3125               // N_EDGES/256
#define PREP_B (CVTX_B + CVTW_B + HIST_B)

typedef __attribute__((ext_vector_type(8))) short bf16x8;
typedef __attribute__((ext_vector_type(4))) float f32x4;
typedef __attribute__((ext_vector_type(2))) float f32x2;
typedef __attribute__((ext_vector_type(8))) unsigned short ushort8;

#define PRESCALE 2.8853900817779268f   // 2*log2(e)
#define L2E 1.4426950408889634f

static __device__ __forceinline__ unsigned short f2bf(float f) {
    __hip_bfloat16 h = __float2bfloat16(f);
    return *reinterpret_cast<unsigned short*>(&h);
}
static __device__ __forceinline__ float bf_lo(unsigned int w) {
    return __uint_as_float(w << 16);
}
static __device__ __forceinline__ float bf_hi(unsigned int w) {
    return __uint_as_float(w & 0xFFFF0000u);
}
// 2^x via single HW instruction (v_exp_f32)
static __device__ __forceinline__ float exp2_hw(float x) {
    float r;
    asm("v_exp_f32 %0, %1" : "=v"(r) : "v"(x));
    return r;
}

// ---------------- prep (NO LDS): cvt_x(bf16+fp8) | cvt_fcW | hist
__global__ __launch_bounds__(256) void prep_kernel(const float* __restrict__ x,
                                                   unsigned short* __restrict__ xb2,
                                                   unsigned char* __restrict__ xf8,
                                                   const float* __restrict__ fcW,
                                                   unsigned short* __restrict__ fcWb,
                                                   const int* __restrict__ dstp,
                                                   int* __restrict__ deg,
                                                   unsigned short* __restrict__ posin) {
    int bid = blockIdx.x;
    int tid = threadIdx.x;
    if (bid < CVTX_B) {
        // ---- x fp32 [b][node][feat] -> bf16 + fp8 interleaved [node][b][feat]
        int t = bid * 256 + tid;
        const float4* in4 = (const float4*)x;
        float4 a = in4[2 * t], b = in4[2 * t + 1];
        ushort8 o;
        o[0] = f2bf(a.x); o[1] = f2bf(a.y); o[2] = f2bf(a.z); o[3] = f2bf(a.w);
        o[4] = f2bf(b.x); o[5] = f2bf(b.y); o[6] = f2bf(b.z); o[7] = f2bf(b.w);
        int f0 = t * 8;
        int bb = f0 >= N_NODES * WFEAT;
        int rem = f0 - bb * (N_NODES * WFEAT);
        int node = rem >> 7, feat = rem & 127;
        *reinterpret_cast<ushort8*>(&xb2[(size_t)node * 256 + bb * 128 + feat]) = o;
        // fp8 e4m3 copy for the agg gather path (HW packed convert)
        int w0 = __builtin_amdgcn_cvt_pk_fp8_f32(a.x, a.y, 0, false);
        w0     = __builtin_amdgcn_cvt_pk_fp8_f32(a.z, a.w, w0, true);
        int w1 = __builtin_amdgcn_cvt_pk_fp8_f32(b.x, b.y, 0, false);
        w1     = __builtin_amdgcn_cvt_pk_fp8_f32(b.z, b.w, w1, true);
        uint2 pk; pk.x = (unsigned int)w0; pk.y = (unsigned int)w1;
        *reinterpret_cast<uint2*>(&xf8[(size_t)node * 256 + bb * 128 + feat]) = pk;
    } else if (bid < CVTX_B + CVTW_B) {
        // ---- fcW fp32 -> bf16
        int t = (bid - CVTX_B) * 256 + tid;
        const float4* in4 = (const float4*)fcW;
        float4 a = in4[2 * t], b = in4[2 * t + 1];
        ushort8 o;
        o[0] = f2bf(a.x); o[1] = f2bf(a.y); o[2] = f2bf(a.z); o[3] = f2bf(a.w);
        o[4] = f2bf(b.x); o[5] = f2bf(b.y); o[6] = f2bf(b.z); o[7] = f2bf(b.w);
        *reinterpret_cast<ushort8*>(&fcWb[8 * t]) = o;
    } else {
        // ---- dst-degree histogram; atomic return value = within-node slot (u16)
        int e = (bid - CVTX_B - CVTW_B) * 256 + tid;
        int d = dstp[e];
        posin[e] = (unsigned short)atomicAdd(&deg[d], 1);
    }
}

// ---------------- proj via MFMA: [eq|ek] = emb @ [Wq;Wk]^T, prescaled -> bf16
__global__ __launch_bounds__(256) void proj_mfma(const float* __restrict__ emb,
                                                 const float* __restrict__ Wq,
                                                 const float* __restrict__ Wk,
                                                 unsigned short* __restrict__ eqb,
                                                 unsigned short* __restrict__ ekb) {
    __shared__ unsigned short As[128 * 64];   // 16 KB, swizzled [r][k]
    __shared__ unsigned short Bs[128 * 64];   // 16 KB, swizzled [n][k]
    int tid = threadIdx.x;
    int wave = tid >> 6, lane = tid & 63;
    int wm = wave >> 1, wn = wave & 1;
    int row0 = blockIdx.x * 128;

#pragma unroll
    for (int c = 0; c < 4; ++c) {
        int idx = (c * 256 + tid) * 8;       // element idx in 128x64 tile
        int r = idx >> 6, k = idx & 63;
        int byte = (r * 128 + k * 2) ^ ((r & 7) << 4);

        int node = row0 + r;
        ushort8 o = {};
        if (node < N_NODES) {
            const float4* p = (const float4*)(emb + (size_t)node * DD + k);
            float4 a = p[0], b = p[1];
            o[0] = f2bf(a.x); o[1] = f2bf(a.y); o[2] = f2bf(a.z); o[3] = f2bf(a.w);
            o[4] = f2bf(b.x); o[5] = f2bf(b.y); o[6] = f2bf(b.z); o[7] = f2bf(b.w);
        }
        *reinterpret_cast<ushort8*>(reinterpret_cast<char*>(As) + byte) = o;

        const float* wsrc = (r < 64) ? (Wq + r * DD + k) : (Wk + (r - 64) * DD + k);
        float4 wa = *(const float4*)wsrc, wb = *((const float4*)wsrc + 1);
        ushort8 ow;
        ow[0] = f2bf(wa.x); ow[1] = f2bf(wa.y); ow[2] = f2bf(wa.z); ow[3] = f2bf(wa.w);
        ow[4] = f2bf(wb.x); ow[5] = f2bf(wb.y); ow[6] = f2bf(wb.z); ow[7] = f2bf(wb.w);
        *reinterpret_cast<ushort8*>(reinterpret_cast<char*>(Bs) + byte) = ow;
    }
    __syncthreads();

    f32x4 acc[4][4] = {};
#pragma unroll
    for (int kk = 0; kk < 2; ++kk) {
        bf16x8 a[4], b[4];
#pragma unroll
        for (int m = 0; m < 4; ++m) {
            int r = wm * 64 + m * 16 + (lane & 15);
            int k = kk * 32 + (lane >> 4) * 8;
            int byte = (r * 128 + k * 2) ^ ((r & 7) << 4);
            a[m] = *reinterpret_cast<bf16x8*>(reinterpret_cast<char*>(As) + byte);
        }
#pragma unroll
        for (int n = 0; n < 4; ++n) {
            int cn = wn * 64 + n * 16 + (lane & 15);
            int k = kk * 32 + (lane >> 4) * 8;
            int byte = (cn * 128 + k * 2) ^ ((cn & 7) << 4);
            b[n] = *reinterpret_cast<bf16x8*>(reinterpret_cast<char*>(Bs) + byte);
        }
#pragma unroll
        for (int m = 0; m < 4; ++m)
#pragma unroll
            for (int n = 0; n < 4; ++n)
                acc[m][n] = __builtin_amdgcn_mfma_f32_16x16x32_bf16(a[m], b[n], acc[m][n], 0, 0, 0);
    }

    // C/D: col = lane&15, row = (lane>>4)*4 + j.  cols 0..63 -> eq, 64..127 -> ek
#pragma unroll
    for (int m = 0; m < 4; ++m) {
#pragma unroll
        for (int n = 0; n < 4; ++n) {
            int col = wn * 64 + n * 16 + (lane & 15);
#pragma unroll
            for (int j = 0; j < 4; ++j) {
                int row = row0 + wm * 64 + m * 16 + (lane >> 4) * 4 + j;
                if (row < N_NODES) {
                    unsigned short val = f2bf(PRESCALE * acc[m][n][j]);
                    if (col < 64) eqb[(size_t)row * DD + col] = val;
                    else          ekb[(size_t)row * DD + col - 64] = val;
                }
            }
        }
    }
}

// ---------------- CSR build: hierarchical scan, 2 dispatches
__global__ void scan_reduce(const int* __restrict__ deg, int* __restrict__ bsum) {
    __shared__ int sh[SCAN_B];
    int i = blockIdx.x * SCAN_B + threadIdx.x;
    sh[threadIdx.x] = (i < N_NODES) ? deg[i] : 0;
    __syncthreads();
    for (int s = SCAN_B / 2; s; s >>= 1) {
        if (threadIdx.x < s) sh[threadIdx.x] += sh[threadIdx.x + s];
        __syncthreads();
    }
    if (threadIdx.x == 0) bsum[blockIdx.x] = sh[0];
}

// each block redundantly scans the raw bsum[] to get its own prefix (no 3rd kernel)
__global__ void scan_final(const int* __restrict__ deg, const int* __restrict__ bsum,
                           int* __restrict__ rowptr) {
    __shared__ int shb[SCAN_B];
    __shared__ int sh[SCAN_B];
    int tid = threadIdx.x;
    int bv = (tid < NBLK) ? bsum[tid] : 0;
    shb[tid] = bv;
    __syncthreads();
    for (int s = 1; s < SCAN_B; s <<= 1) {
        int t = (tid >= s) ? shb[tid - s] : 0;
        __syncthreads();
        shb[tid] += t;
        __syncthreads();
    }
    int myprefix = (blockIdx.x == 0) ? 0 : shb[blockIdx.x - 1];

    int i = blockIdx.x * SCAN_B + tid;
    int v = (i < N_NODES) ? deg[i] : 0;
    sh[tid] = v;
    __syncthreads();
    for (int s = 1; s < SCAN_B; s <<= 1) {
        int t = 0;
        if (tid >= s) t = sh[tid - s];
        __syncthreads();
        sh[tid] += t;
        __syncthreads();
    }
    if (i < N_NODES) {
        int excl = sh[tid] - v + myprefix;
        rowptr[i] = excl;
        if (i == N_NODES - 1) rowptr[N_NODES] = excl + v;
    }
}

// atomic-free scatter, 4 edges/thread with vectorized loads
__global__ void scatter_kernel(const int* __restrict__ src, const int* __restrict__ dst,
                               const int* __restrict__ rowptr,
                               const unsigned short* __restrict__ posin,
                               int* __restrict__ src_sorted) {
    int t = blockIdx.x * blockDim.x + threadIdx.x;
    int e4 = t * 4;
    if (e4 + 3 < N_EDGES) {
        int4 d4 = *reinterpret_cast<const int4*>(dst + e4);
        ushort4 p4 = *reinterpret_cast<const ushort4*>(posin + e4);
        int4 s4 = *reinterpret_cast<const int4*>(src + e4);
        src_sorted[rowptr[d4.x] + p4.x] = s4.x;
        src_sorted[rowptr[d4.y] + p4.y] = s4.y;
        src_sorted[rowptr[d4.z] + p4.z] = s4.z;
        src_sorted[rowptr[d4.w] + p4.w] = s4.w;
    } else {
        for (int e = e4; e < N_EDGES; ++e)
            src_sorted[rowptr[dst[e]] + posin[e]] = src[e];
    }
}

// safe clamped CSR index (handles deg==0 without OOB)
static __device__ __forceinline__ int pidx(int p, int beg, int end) {
    return (p < end) ? p : ((end > beg) ? (end - 1) : 0);
}

// ---------------- Fused score + softmax + aggregation, 2-stage pipelined.
// One wave per dst node; 4 edges/iter, one per 16-lane group.
// Score: lane hl handles dims 4hl..4hl+3 (bf16 eq/ek); Σv·tanh = Vtot − 2Σv·r.
// Agg: lane hl holds feats 8hl..8hl+7 per batch gathered as fp8 (8 B/batch),
// unpacked with v_cvt_pk_f32_fp8; next iteration's loads issued early.
__global__ __launch_bounds__(256) void agg_fused(const unsigned short* __restrict__ eqb,
                                                 const unsigned short* __restrict__ ekb,
                                                 const float* __restrict__ v,
                                                 const unsigned char* __restrict__ xf8,
                                                 const int* __restrict__ rowptr,
                                                 const int* __restrict__ src_sorted,
                                                 unsigned short* __restrict__ aggb2) {
    int node = (blockIdx.x * 256 + threadIdx.x) >> 6;
    if (node >= N_NODES) return;
    int lane = threadIdx.x & 63;
    int g = lane >> 4, hl = lane & 15;

    uint2 eku = *reinterpret_cast<const uint2*>(ekb + (size_t)node * DD + 4 * hl);
    float k0 = bf_lo(eku.x), k1 = bf_hi(eku.x), k2 = bf_lo(eku.y), k3 = bf_hi(eku.y);
    float4 vv = *reinterpret_cast<const float4*>(v + 4 * hl);
    float vs = vv.x + vv.y + vv.z + vv.w;
    vs += __shfl_xor(vs, 1); vs += __shfl_xor(vs, 2);
    vs += __shfl_xor(vs, 4); vs += __shfl_xor(vs, 8);
    float vtotl2 = vs * L2E;

    int beg = rowptr[node], end = rowptr[node + 1];
    int nIter = (end - beg + 3) >> 2;

    float sum = 0.f;
    f32x2 a0[4] = {}, a1[4] = {};

    // stage-0 loads
    int s = src_sorted[pidx(beg + g, beg, end)];
    uint2 equ = *reinterpret_cast<const uint2*>(eqb + (size_t)s * DD + 4 * hl);
    const unsigned char* xr = xf8 + (size_t)s * 256 + 8 * hl;
    uint2 u0 = *reinterpret_cast<const uint2*>(xr);
    uint2 u1 = *reinterpret_cast<const uint2*>(xr + 128);

    for (int i = 0; i < nIter; ++i) {
        bool valid = (beg + 4 * i + g) < end;
        // issue next iteration's loads (hide gather latency under score math)
        int sn = src_sorted[pidx(beg + 4 * (i + 1) + g, beg, end)];
        uint2 equn = *reinterpret_cast<const uint2*>(eqb + (size_t)sn * DD + 4 * hl);
        const unsigned char* xrn = xf8 + (size_t)sn * 256 + 8 * hl;
        uint2 u0n = *reinterpret_cast<const uint2*>(xrn);
        uint2 u1n = *reinterpret_cast<const uint2*>(xrn + 128);

        float s0 = bf_lo(equ.x) + k0, s1 = bf_hi(equ.x) + k1;
        float s2 = bf_lo(equ.y) + k2, s3 = bf_hi(equ.y) + k3;
        float r =      vv.x * __builtin_amdgcn_rcpf(exp2_hw(s0) + 1.f);
        r = fmaf(vv.y, __builtin_amdgcn_rcpf(exp2_hw(s1) + 1.f), r);
        r = fmaf(vv.z, __builtin_amdgcn_rcpf(exp2_hw(s2) + 1.f), r);
        r = fmaf(vv.w, __builtin_amdgcn_rcpf(exp2_hw(s3) + 1.f), r);
        r += __shfl_xor(r, 1); r += __shfl_xor(r, 2);
        r += __shfl_xor(r, 4); r += __shfl_xor(r, 8);
        float w = exp2_hw(fmaf(-2.f * L2E, r, vtotl2));
        w = valid ? w : 0.f;
        sum += w;

        f32x2 p;
        p = __builtin_amdgcn_cvt_pk_f32_fp8((int)u0.x, false); a0[0] += w * p;
        p = __builtin_amdgcn_cvt_pk_f32_fp8((int)u0.x, true);  a0[1] += w * p;
        p = __builtin_amdgcn_cvt_pk_f32_fp8((int)u0.y, false); a0[2] += w * p;
        p = __builtin_amdgcn_cvt_pk_f32_fp8((int)u0.y, true);  a0[3] += w * p;
        p = __builtin_amdgcn_cvt_pk_f32_fp8((int)u1.x, false); a1[0] += w * p;
        p = __builtin_amdgcn_cvt_pk_f32_fp8((int)u1.x, true);  a1[1] += w * p;
        p = __builtin_amdgcn_cvt_pk_f32_fp8((int)u1.y, false); a1[2] += w * p;
        p = __builtin_amdgcn_cvt_pk_f32_fp8((int)u1.y, true);  a1[3] += w * p;

        equ = equn; u0 = u0n; u1 = u1n;
    }

    // combine the four 16-lane groups
    sum += __shfl_xor(sum, 16); sum += __shfl_xor(sum, 32);
#pragma unroll
    for (int j = 0; j < 4; ++j) {
        a0[j].x += __shfl_xor(a0[j].x, 16); a0[j].x += __shfl_xor(a0[j].x, 32);
        a0[j].y += __shfl_xor(a0[j].y, 16); a0[j].y += __shfl_xor(a0[j].y, 32);
        a1[j].x += __shfl_xor(a1[j].x, 16); a1[j].x += __shfl_xor(a1[j].x, 32);
        a1[j].y += __shfl_xor(a1[j].y, 16); a1[j].y += __shfl_xor(a1[j].y, 32);
    }
    float inv = __builtin_amdgcn_rcpf(sum + 1e-8f);

    if (g < 2) {
        float c0 = (g ? a1[0].x : a0[0].x) * inv, c1 = (g ? a1[0].y : a0[0].y) * inv;
        float c2 = (g ? a1[1].x : a0[1].x) * inv, c3 = (g ? a1[1].y : a0[1].y) * inv;
        float c4 = (g ? a1[2].x : a0[2].x) * inv, c5 = (g ? a1[2].y : a0[2].y) * inv;
        float c6 = (g ? a1[3].x : a0[3].x) * inv, c7 = (g ? a1[3].y : a0[3].y) * inv;
        uint4 o;
        o.x = (unsigned int)f2bf(c0) | ((unsigned int)f2bf(c1) << 16);
        o.y = (unsigned int)f2bf(c2) | ((unsigned int)f2bf(c3) << 16);
        o.z = (unsigned int)f2bf(c4) | ((unsigned int)f2bf(c5) << 16);
        o.w = (unsigned int)f2bf(c6) | ((unsigned int)f2bf(c7) << 16);
        *reinterpret_cast<uint4*>(&aggb2[(size_t)node * 256 + (size_t)g * 128 + 8 * hl]) = o;
    }
}

// ---------------- out = relu([x, agg] @ fcW^T + fcb) via bf16 MFMA
// A rows are batch-major [b*N+node]; xb2/aggb2 are interleaved [node][b][128].
__global__ __launch_bounds__(256) void fc_mfma(const unsigned short* __restrict__ xb2,
                                               const unsigned short* __restrict__ aggb2,
                                               const unsigned short* __restrict__ fcWb,
                                               const float* __restrict__ fcb,
                                               float* __restrict__ out) {
    __shared__ unsigned short As[128 * 64];   // 16 KB, swizzled [r][k]
    __shared__ unsigned short Bs[128 * 64];   // 16 KB, swizzled [n][k]
    int tid = threadIdx.x;
    int wave = tid >> 6, lane = tid & 63;
    int wm = wave >> 1, wn = wave & 1;
    int row0 = blockIdx.x * 128;

    f32x4 acc[4][4] = {};

    for (int ks = 0; ks < 4; ++ks) {
        const unsigned short* Asrc = (ks < 2) ? xb2 : aggb2;
        int kbase = (ks & 1) * 64;
        __syncthreads();
#pragma unroll
        for (int c = 0; c < 4; ++c) {
            int idx = (c * 256 + tid) * 8;       // element idx in 128x64 tile
            int r = idx >> 6, k = idx & 63;
            int row = row0 + r;
            ulonglong2 val = make_ulonglong2(0ull, 0ull);
            if (row < NROWS) {
                int batch = row >= N_NODES;
                int nd = row - (batch ? N_NODES : 0);
                val = *reinterpret_cast<const ulonglong2*>(
                        &Asrc[(size_t)nd * 256 + batch * 128 + kbase + k]);
            }
            int byte = (r * 128 + k * 2) ^ ((r & 7) << 4);
            *reinterpret_cast<ulonglong2*>(reinterpret_cast<char*>(As) + byte) = val;

            ulonglong2 wv = *reinterpret_cast<const ulonglong2*>(&fcWb[(size_t)r * 256 + ks * 64 + k]);
            *reinterpret_cast<ulonglong2*>(reinterpret_cast<char*>(Bs) + byte) = wv;
        }
        __syncthreads();
#pragma unroll
        for (int kk = 0; kk < 2; ++kk) {
            bf16x8 a[4], b[4];
#pragma unroll
            for (int m = 0; m < 4; ++m) {
                int r = wm * 64 + m * 16 + (lane & 15);
                int k = kk * 32 + (lane >> 4) * 8;
                int byte = (r * 128 + k * 2) ^ ((r & 7) << 4);
                a[m] = *reinterpret_cast<bf16x8*>(reinterpret_cast<char*>(As) + byte);
            }
#pragma unroll
            for (int n = 0; n < 4; ++n) {
                int cn = wn * 64 + n * 16 + (lane & 15);
                int k = kk * 32 + (lane >> 4) * 8;
                int byte = (cn * 128 + k * 2) ^ ((cn & 7) << 4);
                b[n] = *reinterpret_cast<bf16x8*>(reinterpret_cast<char*>(Bs) + byte);
            }
#pragma unroll
            for (int m = 0; m < 4; ++m)
#pragma unroll
                for (int n = 0; n < 4; ++n)
                    acc[m][n] = __builtin_amdgcn_mfma_f32_16x16x32_bf16(a[m], b[n], acc[m][n], 0, 0, 0);
        }
    }
    // C/D layout: col = lane&15, row = (lane>>4)*4 + j
#pragma unroll
    for (int m = 0; m < 4; ++m) {
#pragma unroll
        for (int n = 0; n < 4; ++n) {
            int col = wn * 64 + n * 16 + (lane & 15);
            float bias = fcb[col];
#pragma unroll
            for (int j = 0; j < 4; ++j) {
                int row = row0 + wm * 64 + m * 16 + (lane >> 4) * 4 + j;
                if (row < NROWS)
                    out[(size_t)row * OUTD + col] = fmaxf(acc[m][n][j] + bias, 0.f);
            }
        }
    }
}

extern "C" void kernel_launch(void* const* d_in, const int* in_sizes, int n_in,
                              void* d_out, int out_size, void* d_ws, size_t ws_size,
                              hipStream_t stream) {
    const float* x    = (const float*)d_in[0];
    const float* emb  = (const float*)d_in[1];
    const int*   eidx = (const int*)d_in[2];
    const float* Wq   = (const float*)d_in[3];
    const float* Wk   = (const float*)d_in[4];
    const float* v    = (const float*)d_in[5];
    const float* fcW  = (const float*)d_in[6];
    const float* fcb  = (const float*)d_in[7];
    float* out = (float*)d_out;

    char* ws = (char*)d_ws;
    unsigned short* eqb  = (unsigned short*)ws;                  ws += (size_t)N_NODES * DD * 2;
    unsigned short* ekb  = (unsigned short*)ws;                  ws += (size_t)N_NODES * DD * 2;
    unsigned short* xb2  = (unsigned short*)ws;                  ws += (size_t)NROWS * WFEAT * 2;
    unsigned char*  xf8  = (unsigned char*)ws;                   ws += (size_t)NROWS * WFEAT;
    unsigned short* aggb2= (unsigned short*)ws;                  ws += (size_t)NROWS * WFEAT * 2;
    unsigned short* fcWb = (unsigned short*)ws;                  ws += (size_t)OUTD * 256 * 2;
    int* deg        = (int*)ws;                                  ws += (size_t)N_NODES * 4;
    int* rowptr     = (int*)ws;                                  ws += (size_t)(N_NODES + 1) * 4 + 12;
    unsigned short* posin = (unsigned short*)ws;                 ws += (size_t)N_EDGES * 2;
    int* bsum       = (int*)ws;                                  ws += 256 * 4;
    int* src_sorted = (int*)ws;

    const int* srcp = eidx;
    const int* dstp = eidx + N_EDGES;

    hipMemsetAsync(deg, 0, (size_t)N_NODES * sizeof(int), stream);

    prep_kernel<<<PREP_B, 256, 0, stream>>>(x, xb2, xf8, fcW, fcWb, dstp, deg, posin);
    proj_mfma<<<PROJ_TB, 256, 0, stream>>>(emb, Wq, Wk, eqb, ekb);
    scan_reduce<<<NBLK, SCAN_B, 0, stream>>>(deg, bsum);
    scan_final<<<NBLK, SCAN_B, 0, stream>>>(deg, bsum, rowptr);
    scatter_kernel<<<(N_EDGES / 4 + 255) / 256, 256, 0, stream>>>(srcp, dstp, rowptr, posin,
                                                                  src_sorted);
    agg_fused<<<(N_NODES * 64 + 255) / 256, 256, 0, stream>>>(eqb, ekb, v, xf8, rowptr,
                                                              src_sorted, aggb2);
    fc_mfma<<<(NROWS + 127) / 128, 256, 0, stream>>>(xb2, aggb2, fcWb, fcb, out);
}

// Round 16
// 165.450 us; speedup vs baseline: 1.0146x; 1.0146x over previous
//
#include <hip/hip_runtime.h>
#include <hip/hip_bf16.h>
#include <math.h>

#define N_NODES 50000
#define N_EDGES 800000
#define BB 2
#define WFEAT 128
#define DD 64
#define OUTD 128
#define NROWS (BB * N_NODES)      // 100000
#define SCAN_B 256
#define NBLK ((N_NODES + SCAN_B - 1) / SCAN_B)   // 196

#define PROJ_TB ((N_NODES + 127) / 128)          // 391
#define CVTX_B 6250               // NROWS*WFEAT/8/256
#define CVTW_B 16                 // OUTD*256/8/256
#define HIST_B 3125               // N_EDGES/256
#define PREP_B (CVTX_B + CVTW_B + HIST_B)

typedef __attribute__((ext_vector_type(8))) short bf16x8;
typedef __attribute__((ext_vector_type(4))) float f32x4;
typedef __attribute__((ext_vector_type(2))) float f32x2;
typedef __attribute__((ext_vector_type(8))) unsigned short ushort8;

#define PRESCALE 2.8853900817779268f   // 2*log2(e)
#define L2E 1.4426950408889634f

static __device__ __forceinline__ unsigned short f2bf(float f) {
    __hip_bfloat16 h = __float2bfloat16(f);
    return *reinterpret_cast<unsigned short*>(&h);
}
static __device__ __forceinline__ float bf_lo(unsigned int w) {
    return __uint_as_float(w << 16);
}
static __device__ __forceinline__ float bf_hi(unsigned int w) {
    return __uint_as_float(w & 0xFFFF0000u);
}
// 2^x via single HW instruction (v_exp_f32)
static __device__ __forceinline__ float exp2_hw(float x) {
    float r;
    asm("v_exp_f32 %0, %1" : "=v"(r) : "v"(x));
    return r;
}
// x + row_ror(x): rotation-add within a 16-lane DPP row (full-rate VALU, no LDS)
template <int CTRL>
static __device__ __forceinline__ float ror_add(float x) {
    int xi = __float_as_int(x);
    int r = __builtin_amdgcn_update_dpp(xi, xi, CTRL, 0xF, 0xF, true);
    return x + __int_as_float(r);
}
// full 16-lane-row sum via ror 8/4/2/1
static __device__ __forceinline__ float row_reduce(float x) {
    x = ror_add<0x128>(x);   // row_ror:8
    x = ror_add<0x124>(x);   // row_ror:4
    x = ror_add<0x122>(x);   // row_ror:2
    x = ror_add<0x121>(x);   // row_ror:1
    return x;
}

// ---------------- prep (NO LDS): cvt_x(bf16+fp8) | cvt_fcW | hist
__global__ __launch_bounds__(256) void prep_kernel(const float* __restrict__ x,
                                                   unsigned short* __restrict__ xb2,
                                                   unsigned char* __restrict__ xf8,
                                                   const float* __restrict__ fcW,
                                                   unsigned short* __restrict__ fcWb,
                                                   const int* __restrict__ dstp,
                                                   int* __restrict__ deg,
                                                   unsigned short* __restrict__ posin) {
    int bid = blockIdx.x;
    int tid = threadIdx.x;
    if (bid < CVTX_B) {
        // ---- x fp32 [b][node][feat] -> bf16 + fp8 interleaved [node][b][feat]
        int t = bid * 256 + tid;
        const float4* in4 = (const float4*)x;
        float4 a = in4[2 * t], b = in4[2 * t + 1];
        ushort8 o;
        o[0] = f2bf(a.x); o[1] = f2bf(a.y); o[2] = f2bf(a.z); o[3] = f2bf(a.w);
        o[4] = f2bf(b.x); o[5] = f2bf(b.y); o[6] = f2bf(b.z); o[7] = f2bf(b.w);
        int f0 = t * 8;
        int bb = f0 >= N_NODES * WFEAT;
        int rem = f0 - bb * (N_NODES * WFEAT);
        int node = rem >> 7, feat = rem & 127;
        *reinterpret_cast<ushort8*>(&xb2[(size_t)node * 256 + bb * 128 + feat]) = o;
        // fp8 e4m3 copy for the agg gather path (HW packed convert)
        int w0 = __builtin_amdgcn_cvt_pk_fp8_f32(a.x, a.y, 0, false);
        w0     = __builtin_amdgcn_cvt_pk_fp8_f32(a.z, a.w, w0, true);
        int w1 = __builtin_amdgcn_cvt_pk_fp8_f32(b.x, b.y, 0, false);
        w1     = __builtin_amdgcn_cvt_pk_fp8_f32(b.z, b.w, w1, true);
        uint2 pk; pk.x = (unsigned int)w0; pk.y = (unsigned int)w1;
        *reinterpret_cast<uint2*>(&xf8[(size_t)node * 256 + bb * 128 + feat]) = pk;
    } else if (bid < CVTX_B + CVTW_B) {
        // ---- fcW fp32 -> bf16
        int t = (bid - CVTX_B) * 256 + tid;
        const float4* in4 = (const float4*)fcW;
        float4 a = in4[2 * t], b = in4[2 * t + 1];
        ushort8 o;
        o[0] = f2bf(a.x); o[1] = f2bf(a.y); o[2] = f2bf(a.z); o[3] = f2bf(a.w);
        o[4] = f2bf(b.x); o[5] = f2bf(b.y); o[6] = f2bf(b.z); o[7] = f2bf(b.w);
        *reinterpret_cast<ushort8*>(&fcWb[8 * t]) = o;
    } else {
        // ---- dst-degree histogram; atomic return value = within-node slot (u16)
        int e = (bid - CVTX_B - CVTW_B) * 256 + tid;
        int d = dstp[e];
        posin[e] = (unsigned short)atomicAdd(&deg[d], 1);
    }
}

// ---------------- proj via MFMA: [eq|ek] = emb @ [Wq;Wk]^T, prescaled -> bf16
__global__ __launch_bounds__(256) void proj_mfma(const float* __restrict__ emb,
                                                 const float* __restrict__ Wq,
                                                 const float* __restrict__ Wk,
                                                 unsigned short* __restrict__ eqb,
                                                 unsigned short* __restrict__ ekb) {
    __shared__ unsigned short As[128 * 64];   // 16 KB, swizzled [r][k]
    __shared__ unsigned short Bs[128 * 64];   // 16 KB, swizzled [n][k]
    int tid = threadIdx.x;
    int wave = tid >> 6, lane = tid & 63;
    int wm = wave >> 1, wn = wave & 1;
    int row0 = blockIdx.x * 128;

#pragma unroll
    for (int c = 0; c < 4; ++c) {
        int idx = (c * 256 + tid) * 8;       // element idx in 128x64 tile
        int r = idx >> 6, k = idx & 63;
        int byte = (r * 128 + k * 2) ^ ((r & 7) << 4);

        int node = row0 + r;
        ushort8 o = {};
        if (node < N_NODES) {
            const float4* p = (const float4*)(emb + (size_t)node * DD + k);
            float4 a = p[0], b = p[1];
            o[0] = f2bf(a.x); o[1] = f2bf(a.y); o[2] = f2bf(a.z); o[3] = f2bf(a.w);
            o[4] = f2bf(b.x); o[5] = f2bf(b.y); o[6] = f2bf(b.z); o[7] = f2bf(b.w);
        }
        *reinterpret_cast<ushort8*>(reinterpret_cast<char*>(As) + byte) = o;

        const float* wsrc = (r < 64) ? (Wq + r * DD + k) : (Wk + (r - 64) * DD + k);
        float4 wa = *(const float4*)wsrc, wb = *((const float4*)wsrc + 1);
        ushort8 ow;
        ow[0] = f2bf(wa.x); ow[1] = f2bf(wa.y); ow[2] = f2bf(wa.z); ow[3] = f2bf(wa.w);
        ow[4] = f2bf(wb.x); ow[5] = f2bf(wb.y); ow[6] = f2bf(wb.z); ow[7] = f2bf(wb.w);
        *reinterpret_cast<ushort8*>(reinterpret_cast<char*>(Bs) + byte) = ow;
    }
    __syncthreads();

    f32x4 acc[4][4] = {};
#pragma unroll
    for (int kk = 0; kk < 2; ++kk) {
        bf16x8 a[4], b[4];
#pragma unroll
        for (int m = 0; m < 4; ++m) {
            int r = wm * 64 + m * 16 + (lane & 15);
            int k = kk * 32 + (lane >> 4) * 8;
            int byte = (r * 128 + k * 2) ^ ((r & 7) << 4);
            a[m] = *reinterpret_cast<bf16x8*>(reinterpret_cast<char*>(As) + byte);
        }
#pragma unroll
        for (int n = 0; n < 4; ++n) {
            int cn = wn * 64 + n * 16 + (lane & 15);
            int k = kk * 32 + (lane >> 4) * 8;
            int byte = (cn * 128 + k * 2) ^ ((cn & 7) << 4);
            b[n] = *reinterpret_cast<bf16x8*>(reinterpret_cast<char*>(Bs) + byte);
        }
#pragma unroll
        for (int m = 0; m < 4; ++m)
#pragma unroll
            for (int n = 0; n < 4; ++n)
                acc[m][n] = __builtin_amdgcn_mfma_f32_16x16x32_bf16(a[m], b[n], acc[m][n], 0, 0, 0);
    }

    // C/D: col = lane&15, row = (lane>>4)*4 + j.  cols 0..63 -> eq, 64..127 -> ek
#pragma unroll
    for (int m = 0; m < 4; ++m) {
#pragma unroll
        for (int n = 0; n < 4; ++n) {
            int col = wn * 64 + n * 16 + (lane & 15);
#pragma unroll
            for (int j = 0; j < 4; ++j) {
                int row = row0 + wm * 64 + m * 16 + (lane >> 4) * 4 + j;
                if (row < N_NODES) {
                    unsigned short val = f2bf(PRESCALE * acc[m][n][j]);
                    if (col < 64) eqb[(size_t)row * DD + col] = val;
                    else          ekb[(size_t)row * DD + col - 64] = val;
                }
            }
        }
    }
}

// ---------------- CSR build: hierarchical scan, 2 dispatches
__global__ void scan_reduce(const int* __restrict__ deg, int* __restrict__ bsum) {
    __shared__ int sh[SCAN_B];
    int i = blockIdx.x * SCAN_B + threadIdx.x;
    sh[threadIdx.x] = (i < N_NODES) ? deg[i] : 0;
    __syncthreads();
    for (int s = SCAN_B / 2; s; s >>= 1) {
        if (threadIdx.x < s) sh[threadIdx.x] += sh[threadIdx.x + s];
        __syncthreads();
    }
    if (threadIdx.x == 0) bsum[blockIdx.x] = sh[0];
}

// each block redundantly scans the raw bsum[] to get its own prefix (no 3rd kernel)
__global__ void scan_final(const int* __restrict__ deg, const int* __restrict__ bsum,
                           int* __restrict__ rowptr) {
    __shared__ int shb[SCAN_B];
    __shared__ int sh[SCAN_B];
    int tid = threadIdx.x;
    int bv = (tid < NBLK) ? bsum[tid] : 0;
    shb[tid] = bv;
    __syncthreads();
    for (int s = 1; s < SCAN_B; s <<= 1) {
        int t = (tid >= s) ? shb[tid - s] : 0;
        __syncthreads();
        shb[tid] += t;
        __syncthreads();
    }
    int myprefix = (blockIdx.x == 0) ? 0 : shb[blockIdx.x - 1];

    int i = blockIdx.x * SCAN_B + tid;
    int v = (i < N_NODES) ? deg[i] : 0;
    sh[tid] = v;
    __syncthreads();
    for (int s = 1; s < SCAN_B; s <<= 1) {
        int t = 0;
        if (tid >= s) t = sh[tid - s];
        __syncthreads();
        sh[tid] += t;
        __syncthreads();
    }
    if (i < N_NODES) {
        int excl = sh[tid] - v + myprefix;
        rowptr[i] = excl;
        if (i == N_NODES - 1) rowptr[N_NODES] = excl + v;
    }
}

// atomic-free scatter, 4 edges/thread with vectorized loads; writes 8 pad zeros
// past N_EDGES so agg's prefetch needs no clamp.
__global__ void scatter_kernel(const int* __restrict__ src, const int* __restrict__ dst,
                               const int* __restrict__ rowptr,
                               const unsigned short* __restrict__ posin,
                               int* __restrict__ src_sorted) {
    int t = blockIdx.x * blockDim.x + threadIdx.x;
    if (t < 8) src_sorted[N_EDGES + t] = 0;
    int e4 = t * 4;
    if (e4 + 3 < N_EDGES) {
        int4 d4 = *reinterpret_cast<const int4*>(dst + e4);
        ushort4 p4 = *reinterpret_cast<const ushort4*>(posin + e4);
        int4 s4 = *reinterpret_cast<const int4*>(src + e4);
        src_sorted[rowptr[d4.x] + p4.x] = s4.x;
        src_sorted[rowptr[d4.y] + p4.y] = s4.y;
        src_sorted[rowptr[d4.z] + p4.z] = s4.z;
        src_sorted[rowptr[d4.w] + p4.w] = s4.w;
    } else {
        for (int e = e4; e < N_EDGES; ++e)
            src_sorted[rowptr[dst[e]] + posin[e]] = src[e];
    }
}

// ---------------- Fused score + softmax + aggregation, 2-stage pipelined.
// One wave per dst node; 4 edges/iter, one per 16-lane group (= DPP row).
// Score: lane hl handles dims 4hl..4hl+3 (bf16 eq/ek); Σv·tanh = Vtot − 2Σv·r;
// 16-lane reduce via DPP row_ror adds (no LDS round-trip).
// Agg: fp8 gathers (8 B/batch), unpacked with v_cvt_pk_f32_fp8; next
// iteration's loads issued early (src_sorted is pad-safe, no clamp).
__global__ __launch_bounds__(256) void agg_fused(const unsigned short* __restrict__ eqb,
                                                 const unsigned short* __restrict__ ekb,
                                                 const float* __restrict__ v,
                                                 const unsigned char* __restrict__ xf8,
                                                 const int* __restrict__ rowptr,
                                                 const int* __restrict__ src_sorted,
                                                 unsigned short* __restrict__ aggb2) {
    int node = (blockIdx.x * 256 + threadIdx.x) >> 6;
    if (node >= N_NODES) return;
    int lane = threadIdx.x & 63;
    int g = lane >> 4, hl = lane & 15;

    uint2 eku = *reinterpret_cast<const uint2*>(ekb + (size_t)node * DD + 4 * hl);
    float k0 = bf_lo(eku.x), k1 = bf_hi(eku.x), k2 = bf_lo(eku.y), k3 = bf_hi(eku.y);
    float4 vv = *reinterpret_cast<const float4*>(v + 4 * hl);
    float vs = row_reduce(vv.x + vv.y + vv.z + vv.w);
    float vtotl2 = vs * L2E;

    int beg = rowptr[node], end = rowptr[node + 1];
    int nIter = (end - beg + 3) >> 2;

    float sum = 0.f;
    f32x2 a0[4] = {}, a1[4] = {};

    // stage-0 loads (src_sorted padded: beg+g always safe)
    int s = src_sorted[beg + g];
    uint2 equ = *reinterpret_cast<const uint2*>(eqb + (size_t)s * DD + 4 * hl);
    const unsigned char* xr = xf8 + (size_t)s * 256 + 8 * hl;
    uint2 u0 = *reinterpret_cast<const uint2*>(xr);
    uint2 u1 = *reinterpret_cast<const uint2*>(xr + 128);

    for (int i = 0; i < nIter; ++i) {
        bool valid = (beg + 4 * i + g) < end;
        // issue next iteration's loads (hide gather latency under score math)
        int sn = src_sorted[beg + 4 * (i + 1) + g];
        uint2 equn = *reinterpret_cast<const uint2*>(eqb + (size_t)sn * DD + 4 * hl);
        const unsigned char* xrn = xf8 + (size_t)sn * 256 + 8 * hl;
        uint2 u0n = *reinterpret_cast<const uint2*>(xrn);
        uint2 u1n = *reinterpret_cast<const uint2*>(xrn + 128);

        float s0 = bf_lo(equ.x) + k0, s1 = bf_hi(equ.x) + k1;
        float s2 = bf_lo(equ.y) + k2, s3 = bf_hi(equ.y) + k3;
        float r =      vv.x * __builtin_amdgcn_rcpf(exp2_hw(s0) + 1.f);
        r = fmaf(vv.y, __builtin_amdgcn_rcpf(exp2_hw(s1) + 1.f), r);
        r = fmaf(vv.z, __builtin_amdgcn_rcpf(exp2_hw(s2) + 1.f), r);
        r = fmaf(vv.w, __builtin_amdgcn_rcpf(exp2_hw(s3) + 1.f), r);
        r = row_reduce(r);
        float w = exp2_hw(fmaf(-2.f * L2E, r, vtotl2));
        w = valid ? w : 0.f;
        sum += w;

        f32x2 p;
        p = __builtin_amdgcn_cvt_pk_f32_fp8((int)u0.x, false); a0[0] += w * p;
        p = __builtin_amdgcn_cvt_pk_f32_fp8((int)u0.x, true);  a0[1] += w * p;
        p = __builtin_amdgcn_cvt_pk_f32_fp8((int)u0.y, false); a0[2] += w * p;
        p = __builtin_amdgcn_cvt_pk_f32_fp8((int)u0.y, true);  a0[3] += w * p;
        p = __builtin_amdgcn_cvt_pk_f32_fp8((int)u1.x, false); a1[0] += w * p;
        p = __builtin_amdgcn_cvt_pk_f32_fp8((int)u1.x, true);  a1[1] += w * p;
        p = __builtin_amdgcn_cvt_pk_f32_fp8((int)u1.y, false); a1[2] += w * p;
        p = __builtin_amdgcn_cvt_pk_f32_fp8((int)u1.y, true);  a1[3] += w * p;

        equ = equn; u0 = u0n; u1 = u1n;
    }

    // combine the four 16-lane groups
    sum += __shfl_xor(sum, 16); sum += __shfl_xor(sum, 32);
#pragma unroll
    for (int j = 0; j < 4; ++j) {
        a0[j].x += __shfl_xor(a0[j].x, 16); a0[j].x += __shfl_xor(a0[j].x, 32);
        a0[j].y += __shfl_xor(a0[j].y, 16); a0[j].y += __shfl_xor(a0[j].y, 32);
        a1[j].x += __shfl_xor(a1[j].x, 16); a1[j].x += __shfl_xor(a1[j].x, 32);
        a1[j].y += __shfl_xor(a1[j].y, 16); a1[j].y += __shfl_xor(a1[j].y, 32);
    }
    float inv = __builtin_amdgcn_rcpf(sum + 1e-8f);

    if (g < 2) {
        float c0 = (g ? a1[0].x : a0[0].x) * inv, c1 = (g ? a1[0].y : a0[0].y) * inv;
        float c2 = (g ? a1[1].x : a0[1].x) * inv, c3 = (g ? a1[1].y : a0[1].y) * inv;
        float c4 = (g ? a1[2].x : a0[2].x) * inv, c5 = (g ? a1[2].y : a0[2].y) * inv;
        float c6 = (g ? a1[3].x : a0[3].x) * inv, c7 = (g ? a1[3].y : a0[3].y) * inv;
        uint4 o;
        o.x = (unsigned int)f2bf(c0) | ((unsigned int)f2bf(c1) << 16);
        o.y = (unsigned int)f2bf(c2) | ((unsigned int)f2bf(c3) << 16);
        o.z = (unsigned int)f2bf(c4) | ((unsigned int)f2bf(c5) << 16);
        o.w = (unsigned int)f2bf(c6) | ((unsigned int)f2bf(c7) << 16);
        *reinterpret_cast<uint4*>(&aggb2[(size_t)node * 256 + (size_t)g * 128 + 8 * hl]) = o;
    }
}

// ---------------- out = relu([x, agg] @ fcW^T + fcb) via bf16 MFMA
// A rows are batch-major [b*N+node]; xb2/aggb2 are interleaved [node][b][128].
__global__ __launch_bounds__(256) void fc_mfma(const unsigned short* __restrict__ xb2,
                                               const unsigned short* __restrict__ aggb2,
                                               const unsigned short* __restrict__ fcWb,
                                               const float* __restrict__ fcb,
                                               float* __restrict__ out) {
    __shared__ unsigned short As[128 * 64];   // 16 KB, swizzled [r][k]
    __shared__ unsigned short Bs[128 * 64];   // 16 KB, swizzled [n][k]
    int tid = threadIdx.x;
    int wave = tid >> 6, lane = tid & 63;
    int wm = wave >> 1, wn = wave & 1;
    int row0 = blockIdx.x * 128;

    f32x4 acc[4][4] = {};

    for (int ks = 0; ks < 4; ++ks) {
        const unsigned short* Asrc = (ks < 2) ? xb2 : aggb2;
        int kbase = (ks & 1) * 64;
        __syncthreads();
#pragma unroll
        for (int c = 0; c < 4; ++c) {
            int idx = (c * 256 + tid) * 8;       // element idx in 128x64 tile
            int r = idx >> 6, k = idx & 63;
            int row = row0 + r;
            ulonglong2 val = make_ulonglong2(0ull, 0ull);
            if (row < NROWS) {
                int batch = row >= N_NODES;
                int nd = row - (batch ? N_NODES : 0);
                val = *reinterpret_cast<const ulonglong2*>(
                        &Asrc[(size_t)nd * 256 + batch * 128 + kbase + k]);
            }
            int byte = (r * 128 + k * 2) ^ ((r & 7) << 4);
            *reinterpret_cast<ulonglong2*>(reinterpret_cast<char*>(As) + byte) = val;

            ulonglong2 wv = *reinterpret_cast<const ulonglong2*>(&fcWb[(size_t)r * 256 + ks * 64 + k]);
            *reinterpret_cast<ulonglong2*>(reinterpret_cast<char*>(Bs) + byte) = wv;
        }
        __syncthreads();
#pragma unroll
        for (int kk = 0; kk < 2; ++kk) {
            bf16x8 a[4], b[4];
#pragma unroll
            for (int m = 0; m < 4; ++m) {
                int r = wm * 64 + m * 16 + (lane & 15);
                int k = kk * 32 + (lane >> 4) * 8;
                int byte = (r * 128 + k * 2) ^ ((r & 7) << 4);
                a[m] = *reinterpret_cast<bf16x8*>(reinterpret_cast<char*>(As) + byte);
            }
#pragma unroll
            for (int n = 0; n < 4; ++n) {
                int cn = wn * 64 + n * 16 + (lane & 15);
                int k = kk * 32 + (lane >> 4) * 8;
                int byte = (cn * 128 + k * 2) ^ ((cn & 7) << 4);
                b[n] = *reinterpret_cast<bf16x8*>(reinterpret_cast<char*>(Bs) + byte);
            }
#pragma unroll
            for (int m = 0; m < 4; ++m)
#pragma unroll
                for (int n = 0; n < 4; ++n)
                    acc[m][n] = __builtin_amdgcn_mfma_f32_16x16x32_bf16(a[m], b[n], acc[m][n], 0, 0, 0);
        }
    }
    // C/D layout: col = lane&15, row = (lane>>4)*4 + j
#pragma unroll
    for (int m = 0; m < 4; ++m) {
#pragma unroll
        for (int n = 0; n < 4; ++n) {
            int col = wn * 64 + n * 16 + (lane & 15);
            float bias = fcb[col];
#pragma unroll
            for (int j = 0; j < 4; ++j) {
                int row = row0 + wm * 64 + m * 16 + (lane >> 4) * 4 + j;
                if (row < NROWS)
                    out[(size_t)row * OUTD + col] = fmaxf(acc[m][n][j] + bias, 0.f);
            }
        }
    }
}

extern "C" void kernel_launch(void* const* d_in, const int* in_sizes, int n_in,
                              void* d_out, int out_size, void* d_ws, size_t ws_size,
                              hipStream_t stream) {
    const float* x    = (const float*)d_in[0];
    const float* emb  = (const float*)d_in[1];
    const int*   eidx = (const int*)d_in[2];
    const float* Wq   = (const float*)d_in[3];
    const float* Wk   = (const float*)d_in[4];
    const float* v    = (const float*)d_in[5];
    const float* fcW  = (const float*)d_in[6];
    const float* fcb  = (const float*)d_in[7];
    float* out = (float*)d_out;

    char* ws = (char*)d_ws;
    unsigned short* eqb  = (unsigned short*)ws;                  ws += (size_t)N_NODES * DD * 2;
    unsigned short* ekb  = (unsigned short*)ws;                  ws += (size_t)N_NODES * DD * 2;
    unsigned short* xb2  = (unsigned short*)ws;                  ws += (size_t)NROWS * WFEAT * 2;
    unsigned char*  xf8  = (unsigned char*)ws;                   ws += (size_t)NROWS * WFEAT;
    unsigned short* aggb2= (unsigned short*)ws;                  ws += (size_t)NROWS * WFEAT * 2;
    unsigned short* fcWb = (unsigned short*)ws;                  ws += (size_t)OUTD * 256 * 2;
    int* deg        = (int*)ws;                                  ws += (size_t)N_NODES * 4;
    int* rowptr     = (int*)ws;                                  ws += (size_t)(N_NODES + 1) * 4 + 12;
    unsigned short* posin = (unsigned short*)ws;                 ws += (size_t)N_EDGES * 2;
    int* bsum       = (int*)ws;                                  ws += 256 * 4;
    int* src_sorted = (int*)ws;   // N_EDGES + 8 (padded)

    const int* srcp = eidx;
    const int* dstp = eidx + N_EDGES;

    hipMemsetAsync(deg, 0, (size_t)N_NODES * sizeof(int), stream);

    prep_kernel<<<PREP_B, 256, 0, stream>>>(x, xb2, xf8, fcW, fcWb, dstp, deg, posin);
    proj_mfma<<<PROJ_TB, 256, 0, stream>>>(emb, Wq, Wk, eqb, ekb);
    scan_reduce<<<NBLK, SCAN_B, 0, stream>>>(deg, bsum);
    scan_final<<<NBLK, SCAN_B, 0, stream>>>(deg, bsum, rowptr);
    scatter_kernel<<<(N_EDGES / 4 + 255) / 256, 256, 0, stream>>>(srcp, dstp, rowptr, posin,
                                                                  src_sorted);
    agg_fused<<<(N_NODES * 64 + 255) / 256, 256, 0, stream>>>(eqb, ekb, v, xf8, rowptr,
                                                              src_sorted, aggb2);
    fc_mfma<<<(NROWS + 127) / 128, 256, 0, stream>>>(xb2, aggb2, fcWb, fcb, out);
}

// Round 17
// 156.540 us; speedup vs baseline: 1.0723x; 1.0569x over previous
//
#include <hip/hip_runtime.h>
#include <hip/hip_bf16.h>
#include <math.h>

#define N_NODES 50000
#define N_EDGES 800000
#define BB 2
#define WFEAT 128
#define DD 64
#define OUTD 128
#define NROWS (BB * N_NODES)      // 100000
#define SCAN_B 256
#define NBLK ((N_NODES + SCAN_B - 1) / SCAN_B)   // 196

#define PROJ_TB ((N_NODES + 127) / 128)          // 391
#define CVTX_B 6250               // NROWS*WFEAT/8/256  (== 2*HIST_B)
#define CVTW_B 16                 // OUTD*256/8/256
#define HIST_B 3125               // N_EDGES/256
#define TRIPLE_B (3 * HIST_B)     // 9375: striped {cvt,cvt,hist} triples
#define PREP_B (TRIPLE_B + CVTW_B)

typedef __attribute__((ext_vector_type(8))) short bf16x8;
typedef __attribute__((ext_vector_type(4))) float f32x4;
typedef __attribute__((ext_vector_type(2))) float f32x2;
typedef __attribute__((ext_vector_type(8))) unsigned short ushort8;

#define PRESCALE 2.8853900817779268f   // 2*log2(e)
#define L2E 1.4426950408889634f

static __device__ __forceinline__ unsigned short f2bf(float f) {
    __hip_bfloat16 h = __float2bfloat16(f);
    return *reinterpret_cast<unsigned short*>(&h);
}
static __device__ __forceinline__ float bf_lo(unsigned int w) {
    return __uint_as_float(w << 16);
}
static __device__ __forceinline__ float bf_hi(unsigned int w) {
    return __uint_as_float(w & 0xFFFF0000u);
}
// 2^x via single HW instruction (v_exp_f32)
static __device__ __forceinline__ float exp2_hw(float x) {
    float r;
    asm("v_exp_f32 %0, %1" : "=v"(r) : "v"(x));
    return r;
}
// x + row_ror(x): rotation-add within a 16-lane DPP row (full-rate VALU, no LDS)
template <int CTRL>
static __device__ __forceinline__ float ror_add(float x) {
    int xi = __float_as_int(x);
    int r = __builtin_amdgcn_update_dpp(xi, xi, CTRL, 0xF, 0xF, true);
    return x + __int_as_float(r);
}
// full 16-lane-row sum via ror 8/4/2/1
static __device__ __forceinline__ float row_reduce(float x) {
    x = ror_add<0x128>(x);   // row_ror:8
    x = ror_add<0x124>(x);   // row_ror:4
    x = ror_add<0x122>(x);   // row_ror:2
    x = ror_add<0x121>(x);   // row_ror:1
    return x;
}

// ---------------- prep (NO LDS): striped {cvt,cvt,hist} so the atomic-bound
// hist blocks are co-resident with the BW-bound cvt blocks (overlap, not serial).
__global__ __launch_bounds__(256) void prep_kernel(const float* __restrict__ x,
                                                   unsigned short* __restrict__ xb2,
                                                   unsigned char* __restrict__ xf8,
                                                   const float* __restrict__ fcW,
                                                   unsigned short* __restrict__ fcWb,
                                                   const int* __restrict__ dstp,
                                                   int* __restrict__ deg,
                                                   unsigned short* __restrict__ posin) {
    int bid = blockIdx.x;
    int tid = threadIdx.x;
    if (bid < TRIPLE_B) {
        int q = bid / 3;
        int r = bid - q * 3;
        if (r < 2) {
            // ---- x fp32 [b][node][feat] -> bf16 + fp8 interleaved [node][b][feat]
            int t = (q * 2 + r) * 256 + tid;
            const float4* in4 = (const float4*)x;
            float4 a = in4[2 * t], b = in4[2 * t + 1];
            ushort8 o;
            o[0] = f2bf(a.x); o[1] = f2bf(a.y); o[2] = f2bf(a.z); o[3] = f2bf(a.w);
            o[4] = f2bf(b.x); o[5] = f2bf(b.y); o[6] = f2bf(b.z); o[7] = f2bf(b.w);
            int f0 = t * 8;
            int bb = f0 >= N_NODES * WFEAT;
            int rem = f0 - bb * (N_NODES * WFEAT);
            int node = rem >> 7, feat = rem & 127;
            *reinterpret_cast<ushort8*>(&xb2[(size_t)node * 256 + bb * 128 + feat]) = o;
            // fp8 e4m3 copy for the agg gather path (HW packed convert)
            int w0 = __builtin_amdgcn_cvt_pk_fp8_f32(a.x, a.y, 0, false);
            w0     = __builtin_amdgcn_cvt_pk_fp8_f32(a.z, a.w, w0, true);
            int w1 = __builtin_amdgcn_cvt_pk_fp8_f32(b.x, b.y, 0, false);
            w1     = __builtin_amdgcn_cvt_pk_fp8_f32(b.z, b.w, w1, true);
            uint2 pk; pk.x = (unsigned int)w0; pk.y = (unsigned int)w1;
            *reinterpret_cast<uint2*>(&xf8[(size_t)node * 256 + bb * 128 + feat]) = pk;
        } else {
            // ---- dst-degree histogram; atomic return value = within-node slot (u16)
            int e = q * 256 + tid;
            int d = dstp[e];
            posin[e] = (unsigned short)atomicAdd(&deg[d], 1);
        }
    } else {
        // ---- fcW fp32 -> bf16
        int t = (bid - TRIPLE_B) * 256 + tid;
        const float4* in4 = (const float4*)fcW;
        float4 a = in4[2 * t], b = in4[2 * t + 1];
        ushort8 o;
        o[0] = f2bf(a.x); o[1] = f2bf(a.y); o[2] = f2bf(a.z); o[3] = f2bf(a.w);
        o[4] = f2bf(b.x); o[5] = f2bf(b.y); o[6] = f2bf(b.z); o[7] = f2bf(b.w);
        *reinterpret_cast<ushort8*>(&fcWb[8 * t]) = o;
    }
}

// ---------------- proj via MFMA: [eq|ek] = emb @ [Wq;Wk]^T, prescaled -> bf16
__global__ __launch_bounds__(256) void proj_mfma(const float* __restrict__ emb,
                                                 const float* __restrict__ Wq,
                                                 const float* __restrict__ Wk,
                                                 unsigned short* __restrict__ eqb,
                                                 unsigned short* __restrict__ ekb) {
    __shared__ unsigned short As[128 * 64];   // 16 KB, swizzled [r][k]
    __shared__ unsigned short Bs[128 * 64];   // 16 KB, swizzled [n][k]
    int tid = threadIdx.x;
    int wave = tid >> 6, lane = tid & 63;
    int wm = wave >> 1, wn = wave & 1;
    int row0 = blockIdx.x * 128;

#pragma unroll
    for (int c = 0; c < 4; ++c) {
        int idx = (c * 256 + tid) * 8;       // element idx in 128x64 tile
        int r = idx >> 6, k = idx & 63;
        int byte = (r * 128 + k * 2) ^ ((r & 7) << 4);

        int node = row0 + r;
        ushort8 o = {};
        if (node < N_NODES) {
            const float4* p = (const float4*)(emb + (size_t)node * DD + k);
            float4 a = p[0], b = p[1];
            o[0] = f2bf(a.x); o[1] = f2bf(a.y); o[2] = f2bf(a.z); o[3] = f2bf(a.w);
            o[4] = f2bf(b.x); o[5] = f2bf(b.y); o[6] = f2bf(b.z); o[7] = f2bf(b.w);
        }
        *reinterpret_cast<ushort8*>(reinterpret_cast<char*>(As) + byte) = o;

        const float* wsrc = (r < 64) ? (Wq + r * DD + k) : (Wk + (r - 64) * DD + k);
        float4 wa = *(const float4*)wsrc, wb = *((const float4*)wsrc + 1);
        ushort8 ow;
        ow[0] = f2bf(wa.x); ow[1] = f2bf(wa.y); ow[2] = f2bf(wa.z); ow[3] = f2bf(wa.w);
        ow[4] = f2bf(wb.x); ow[5] = f2bf(wb.y); ow[6] = f2bf(wb.z); ow[7] = f2bf(wb.w);
        *reinterpret_cast<ushort8*>(reinterpret_cast<char*>(Bs) + byte) = ow;
    }
    __syncthreads();

    f32x4 acc[4][4] = {};
#pragma unroll
    for (int kk = 0; kk < 2; ++kk) {
        bf16x8 a[4], b[4];
#pragma unroll
        for (int m = 0; m < 4; ++m) {
            int r = wm * 64 + m * 16 + (lane & 15);
            int k = kk * 32 + (lane >> 4) * 8;
            int byte = (r * 128 + k * 2) ^ ((r & 7) << 4);
            a[m] = *reinterpret_cast<bf16x8*>(reinterpret_cast<char*>(As) + byte);
        }
#pragma unroll
        for (int n = 0; n < 4; ++n) {
            int cn = wn * 64 + n * 16 + (lane & 15);
            int k = kk * 32 + (lane >> 4) * 8;
            int byte = (cn * 128 + k * 2) ^ ((cn & 7) << 4);
            b[n] = *reinterpret_cast<bf16x8*>(reinterpret_cast<char*>(Bs) + byte);
        }
#pragma unroll
        for (int m = 0; m < 4; ++m)
#pragma unroll
            for (int n = 0; n < 4; ++n)
                acc[m][n] = __builtin_amdgcn_mfma_f32_16x16x32_bf16(a[m], b[n], acc[m][n], 0, 0, 0);
    }

    // C/D: col = lane&15, row = (lane>>4)*4 + j.  cols 0..63 -> eq, 64..127 -> ek
#pragma unroll
    for (int m = 0; m < 4; ++m) {
#pragma unroll
        for (int n = 0; n < 4; ++n) {
            int col = wn * 64 + n * 16 + (lane & 15);
#pragma unroll
            for (int j = 0; j < 4; ++j) {
                int row = row0 + wm * 64 + m * 16 + (lane >> 4) * 4 + j;
                if (row < N_NODES) {
                    unsigned short val = f2bf(PRESCALE * acc[m][n][j]);
                    if (col < 64) eqb[(size_t)row * DD + col] = val;
                    else          ekb[(size_t)row * DD + col - 64] = val;
                }
            }
        }
    }
}

// ---------------- CSR build: hierarchical scan, 2 dispatches
__global__ void scan_reduce(const int* __restrict__ deg, int* __restrict__ bsum) {
    __shared__ int sh[SCAN_B];
    int i = blockIdx.x * SCAN_B + threadIdx.x;
    sh[threadIdx.x] = (i < N_NODES) ? deg[i] : 0;
    __syncthreads();
    for (int s = SCAN_B / 2; s; s >>= 1) {
        if (threadIdx.x < s) sh[threadIdx.x] += sh[threadIdx.x + s];
        __syncthreads();
    }
    if (threadIdx.x == 0) bsum[blockIdx.x] = sh[0];
}

// each block redundantly scans the raw bsum[] to get its own prefix (no 3rd kernel)
__global__ void scan_final(const int* __restrict__ deg, const int* __restrict__ bsum,
                           int* __restrict__ rowptr) {
    __shared__ int shb[SCAN_B];
    __shared__ int sh[SCAN_B];
    int tid = threadIdx.x;
    int bv = (tid < NBLK) ? bsum[tid] : 0;
    shb[tid] = bv;
    __syncthreads();
    for (int s = 1; s < SCAN_B; s <<= 1) {
        int t = (tid >= s) ? shb[tid - s] : 0;
        __syncthreads();
        shb[tid] += t;
        __syncthreads();
    }
    int myprefix = (blockIdx.x == 0) ? 0 : shb[blockIdx.x - 1];

    int i = blockIdx.x * SCAN_B + tid;
    int v = (i < N_NODES) ? deg[i] : 0;
    sh[tid] = v;
    __syncthreads();
    for (int s = 1; s < SCAN_B; s <<= 1) {
        int t = 0;
        if (tid >= s) t = sh[tid - s];
        __syncthreads();
        sh[tid] += t;
        __syncthreads();
    }
    if (i < N_NODES) {
        int excl = sh[tid] - v + myprefix;
        rowptr[i] = excl;
        if (i == N_NODES - 1) rowptr[N_NODES] = excl + v;
    }
}

// atomic-free scatter, 4 edges/thread with vectorized loads; writes 8 pad zeros
// past N_EDGES so agg's prefetch needs no clamp.
__global__ void scatter_kernel(const int* __restrict__ src, const int* __restrict__ dst,
                               const int* __restrict__ rowptr,
                               const unsigned short* __restrict__ posin,
                               int* __restrict__ src_sorted) {
    int t = blockIdx.x * blockDim.x + threadIdx.x;
    if (t < 8) src_sorted[N_EDGES + t] = 0;
    int e4 = t * 4;
    if (e4 + 3 < N_EDGES) {
        int4 d4 = *reinterpret_cast<const int4*>(dst + e4);
        ushort4 p4 = *reinterpret_cast<const ushort4*>(posin + e4);
        int4 s4 = *reinterpret_cast<const int4*>(src + e4);
        src_sorted[rowptr[d4.x] + p4.x] = s4.x;
        src_sorted[rowptr[d4.y] + p4.y] = s4.y;
        src_sorted[rowptr[d4.z] + p4.z] = s4.z;
        src_sorted[rowptr[d4.w] + p4.w] = s4.w;
    } else {
        for (int e = e4; e < N_EDGES; ++e)
            src_sorted[rowptr[dst[e]] + posin[e]] = src[e];
    }
}

// ---------------- Fused score + softmax + aggregation, 2-stage pipelined.
// One wave per dst node; 4 edges/iter, one per 16-lane group (= DPP row).
// Score: lane hl handles dims 4hl..4hl+3 (bf16 eq/ek); Σv·tanh = Vtot − 2Σv·r;
// 16-lane reduce via DPP row_ror adds (no LDS round-trip).
// Agg: fp8 gathers (8 B/batch), unpacked with v_cvt_pk_f32_fp8; next
// iteration's loads issued early (src_sorted is pad-safe, no clamp).
__global__ __launch_bounds__(256) void agg_fused(const unsigned short* __restrict__ eqb,
                                                 const unsigned short* __restrict__ ekb,
                                                 const float* __restrict__ v,
                                                 const unsigned char* __restrict__ xf8,
                                                 const int* __restrict__ rowptr,
                                                 const int* __restrict__ src_sorted,
                                                 unsigned short* __restrict__ aggb2) {
    int node = (blockIdx.x * 256 + threadIdx.x) >> 6;
    if (node >= N_NODES) return;
    int lane = threadIdx.x & 63;
    int g = lane >> 4, hl = lane & 15;

    uint2 eku = *reinterpret_cast<const uint2*>(ekb + (size_t)node * DD + 4 * hl);
    float k0 = bf_lo(eku.x), k1 = bf_hi(eku.x), k2 = bf_lo(eku.y), k3 = bf_hi(eku.y);
    float4 vv = *reinterpret_cast<const float4*>(v + 4 * hl);
    float vs = row_reduce(vv.x + vv.y + vv.z + vv.w);
    float vtotl2 = vs * L2E;

    int beg = rowptr[node], end = rowptr[node + 1];
    int nIter = (end - beg + 3) >> 2;

    float sum = 0.f;
    f32x2 a0[4] = {}, a1[4] = {};

    // stage-0 loads (src_sorted padded: beg+g always safe)
    int s = src_sorted[beg + g];
    uint2 equ = *reinterpret_cast<const uint2*>(eqb + (size_t)s * DD + 4 * hl);
    const unsigned char* xr = xf8 + (size_t)s * 256 + 8 * hl;
    uint2 u0 = *reinterpret_cast<const uint2*>(xr);
    uint2 u1 = *reinterpret_cast<const uint2*>(xr + 128);

    for (int i = 0; i < nIter; ++i) {
        bool valid = (beg + 4 * i + g) < end;
        // issue next iteration's loads (hide gather latency under score math)
        int sn = src_sorted[beg + 4 * (i + 1) + g];
        uint2 equn = *reinterpret_cast<const uint2*>(eqb + (size_t)sn * DD + 4 * hl);
        const unsigned char* xrn = xf8 + (size_t)sn * 256 + 8 * hl;
        uint2 u0n = *reinterpret_cast<const uint2*>(xrn);
        uint2 u1n = *reinterpret_cast<const uint2*>(xrn + 128);

        float s0 = bf_lo(equ.x) + k0, s1 = bf_hi(equ.x) + k1;
        float s2 = bf_lo(equ.y) + k2, s3 = bf_hi(equ.y) + k3;
        float r =      vv.x * __builtin_amdgcn_rcpf(exp2_hw(s0) + 1.f);
        r = fmaf(vv.y, __builtin_amdgcn_rcpf(exp2_hw(s1) + 1.f), r);
        r = fmaf(vv.z, __builtin_amdgcn_rcpf(exp2_hw(s2) + 1.f), r);
        r = fmaf(vv.w, __builtin_amdgcn_rcpf(exp2_hw(s3) + 1.f), r);
        r = row_reduce(r);
        float w = exp2_hw(fmaf(-2.f * L2E, r, vtotl2));
        w = valid ? w : 0.f;
        sum += w;

        f32x2 p;
        p = __builtin_amdgcn_cvt_pk_f32_fp8((int)u0.x, false); a0[0] += w * p;
        p = __builtin_amdgcn_cvt_pk_f32_fp8((int)u0.x, true);  a0[1] += w * p;
        p = __builtin_amdgcn_cvt_pk_f32_fp8((int)u0.y, false); a0[2] += w * p;
        p = __builtin_amdgcn_cvt_pk_f32_fp8((int)u0.y, true);  a0[3] += w * p;
        p = __builtin_amdgcn_cvt_pk_f32_fp8((int)u1.x, false); a1[0] += w * p;
        p = __builtin_amdgcn_cvt_pk_f32_fp8((int)u1.x, true);  a1[1] += w * p;
        p = __builtin_amdgcn_cvt_pk_f32_fp8((int)u1.y, false); a1[2] += w * p;
        p = __builtin_amdgcn_cvt_pk_f32_fp8((int)u1.y, true);  a1[3] += w * p;

        equ = equn; u0 = u0n; u1 = u1n;
    }

    // combine the four 16-lane groups
    sum += __shfl_xor(sum, 16); sum += __shfl_xor(sum, 32);
#pragma unroll
    for (int j = 0; j < 4; ++j) {
        a0[j].x += __shfl_xor(a0[j].x, 16); a0[j].x += __shfl_xor(a0[j].x, 32);
        a0[j].y += __shfl_xor(a0[j].y, 16); a0[j].y += __shfl_xor(a0[j].y, 32);
        a1[j].x += __shfl_xor(a1[j].x, 16); a1[j].x += __shfl_xor(a1[j].x, 32);
        a1[j].y += __shfl_xor(a1[j].y, 16); a1[j].y += __shfl_xor(a1[j].y, 32);
    }
    float inv = __builtin_amdgcn_rcpf(sum + 1e-8f);

    if (g < 2) {
        float c0 = (g ? a1[0].x : a0[0].x) * inv, c1 = (g ? a1[0].y : a0[0].y) * inv;
        float c2 = (g ? a1[1].x : a0[1].x) * inv, c3 = (g ? a1[1].y : a0[1].y) * inv;
        float c4 = (g ? a1[2].x : a0[2].x) * inv, c5 = (g ? a1[2].y : a0[2].y) * inv;
        float c6 = (g ? a1[3].x : a0[3].x) * inv, c7 = (g ? a1[3].y : a0[3].y) * inv;
        uint4 o;
        o.x = (unsigned int)f2bf(c0) | ((unsigned int)f2bf(c1) << 16);
        o.y = (unsigned int)f2bf(c2) | ((unsigned int)f2bf(c3) << 16);
        o.z = (unsigned int)f2bf(c4) | ((unsigned int)f2bf(c5) << 16);
        o.w = (unsigned int)f2bf(c6) | ((unsigned int)f2bf(c7) << 16);
        *reinterpret_cast<uint4*>(&aggb2[(size_t)node * 256 + (size_t)g * 128 + 8 * hl]) = o;
    }
}

// ---------------- out = relu([x, agg] @ fcW^T + fcb) via bf16 MFMA
// A rows are batch-major [b*N+node]; xb2/aggb2 are interleaved [node][b][128].
__global__ __launch_bounds__(256) void fc_mfma(const unsigned short* __restrict__ xb2,
                                               const unsigned short* __restrict__ aggb2,
                                               const unsigned short* __restrict__ fcWb,
                                               const float* __restrict__ fcb,
                                               float* __restrict__ out) {
    __shared__ unsigned short As[128 * 64];   // 16 KB, swizzled [r][k]
    __shared__ unsigned short Bs[128 * 64];   // 16 KB, swizzled [n][k]
    int tid = threadIdx.x;
    int wave = tid >> 6, lane = tid & 63;
    int wm = wave >> 1, wn = wave & 1;
    int row0 = blockIdx.x * 128;

    f32x4 acc[4][4] = {};

    for (int ks = 0; ks < 4; ++ks) {
        const unsigned short* Asrc = (ks < 2) ? xb2 : aggb2;
        int kbase = (ks & 1) * 64;
        __syncthreads();
#pragma unroll
        for (int c = 0; c < 4; ++c) {
            int idx = (c * 256 + tid) * 8;       // element idx in 128x64 tile
            int r = idx >> 6, k = idx & 63;
            int row = row0 + r;
            ulonglong2 val = make_ulonglong2(0ull, 0ull);
            if (row < NROWS) {
                int batch = row >= N_NODES;
                int nd = row - (batch ? N_NODES : 0);
                val = *reinterpret_cast<const ulonglong2*>(
                        &Asrc[(size_t)nd * 256 + batch * 128 + kbase + k]);
            }
            int byte = (r * 128 + k * 2) ^ ((r & 7) << 4);
            *reinterpret_cast<ulonglong2*>(reinterpret_cast<char*>(As) + byte) = val;

            ulonglong2 wv = *reinterpret_cast<const ulonglong2*>(&fcWb[(size_t)r * 256 + ks * 64 + k]);
            *reinterpret_cast<ulonglong2*>(reinterpret_cast<char*>(Bs) + byte) = wv;
        }
        __syncthreads();
#pragma unroll
        for (int kk = 0; kk < 2; ++kk) {
            bf16x8 a[4], b[4];
#pragma unroll
            for (int m = 0; m < 4; ++m) {
                int r = wm * 64 + m * 16 + (lane & 15);
                int k = kk * 32 + (lane >> 4) * 8;
                int byte = (r * 128 + k * 2) ^ ((r & 7) << 4);
                a[m] = *reinterpret_cast<bf16x8*>(reinterpret_cast<char*>(As) + byte);
            }
#pragma unroll
            for (int n = 0; n < 4; ++n) {
                int cn = wn * 64 + n * 16 + (lane & 15);
                int k = kk * 32 + (lane >> 4) * 8;
                int byte = (cn * 128 + k * 2) ^ ((cn & 7) << 4);
                b[n] = *reinterpret_cast<bf16x8*>(reinterpret_cast<char*>(Bs) + byte);
            }
#pragma unroll
            for (int m = 0; m < 4; ++m)
#pragma unroll
                for (int n = 0; n < 4; ++n)
                    acc[m][n] = __builtin_amdgcn_mfma_f32_16x16x32_bf16(a[m], b[n], acc[m][n], 0, 0, 0);
        }
    }
    // C/D layout: col = lane&15, row = (lane>>4)*4 + j
#pragma unroll
    for (int m = 0; m < 4; ++m) {
#pragma unroll
        for (int n = 0; n < 4; ++n) {
            int col = wn * 64 + n * 16 + (lane & 15);
            float bias = fcb[col];
#pragma unroll
            for (int j = 0; j < 4; ++j) {
                int row = row0 + wm * 64 + m * 16 + (lane >> 4) * 4 + j;
                if (row < NROWS)
                    out[(size_t)row * OUTD + col] = fmaxf(acc[m][n][j] + bias, 0.f);
            }
        }
    }
}

extern "C" void kernel_launch(void* const* d_in, const int* in_sizes, int n_in,
                              void* d_out, int out_size, void* d_ws, size_t ws_size,
                              hipStream_t stream) {
    const float* x    = (const float*)d_in[0];
    const float* emb  = (const float*)d_in[1];
    const int*   eidx = (const int*)d_in[2];
    const float* Wq   = (const float*)d_in[3];
    const float* Wk   = (const float*)d_in[4];
    const float* v    = (const float*)d_in[5];
    const float* fcW  = (const float*)d_in[6];
    const float* fcb  = (const float*)d_in[7];
    float* out = (float*)d_out;

    char* ws = (char*)d_ws;
    unsigned short* eqb  = (unsigned short*)ws;                  ws += (size_t)N_NODES * DD * 2;
    unsigned short* ekb  = (unsigned short*)ws;                  ws += (size_t)N_NODES * DD * 2;
    unsigned short* xb2  = (unsigned short*)ws;                  ws += (size_t)NROWS * WFEAT * 2;
    unsigned char*  xf8  = (unsigned char*)ws;                   ws += (size_t)NROWS * WFEAT;
    unsigned short* aggb2= (unsigned short*)ws;                  ws += (size_t)NROWS * WFEAT * 2;
    unsigned short* fcWb = (unsigned short*)ws;                  ws += (size_t)OUTD * 256 * 2;
    int* deg        = (int*)ws;                                  ws += (size_t)N_NODES * 4;
    int* rowptr     = (int*)ws;                                  ws += (size_t)(N_NODES + 1) * 4 + 12;
    unsigned short* posin = (unsigned short*)ws;                 ws += (size_t)N_EDGES * 2;
    int* bsum       = (int*)ws;                                  ws += 256 * 4;
    int* src_sorted = (int*)ws;   // N_EDGES + 8 (padded)

    const int* srcp = eidx;
    const int* dstp = eidx + N_EDGES;

    hipMemsetAsync(deg, 0, (size_t)N_NODES * sizeof(int), stream);

    prep_kernel<<<PREP_B, 256, 0, stream>>>(x, xb2, xf8, fcW, fcWb, dstp, deg, posin);
    proj_mfma<<<PROJ_TB, 256, 0, stream>>>(emb, Wq, Wk, eqb, ekb);
    scan_reduce<<<NBLK, SCAN_B, 0, stream>>>(deg, bsum);
    scan_final<<<NBLK, SCAN_B, 0, stream>>>(deg, bsum, rowptr);
    scatter_kernel<<<(N_EDGES / 4 + 255) / 256, 256, 0, stream>>>(srcp, dstp, rowptr, posin,
                                                                  src_sorted);
    agg_fused<<<(N_NODES * 64 + 255) / 256, 256, 0, stream>>>(eqb, ekb, v, xf8, rowptr,
                                                              src_sorted, aggb2);
    fc_mfma<<<(NROWS + 127) / 128, 256, 0, stream>>>(xb2, aggb2, fcWb, fcb, out);
}

// Round 18
// 153.578 us; speedup vs baseline: 1.0930x; 1.0193x over previous
//
#include <hip/hip_runtime.h>
#include <hip/hip_bf16.h>
#include <math.h>

#define N_NODES 50000
#define N_EDGES 800000
#define BB 2
#define WFEAT 128
#define DD 64
#define OUTD 128
#define NROWS (BB * N_NODES)      // 100000
#define SCAN_B 256
#define NBLK ((N_NODES + SCAN_B - 1) / SCAN_B)   // 196

#define PROJ_TB ((N_NODES + 127) / 128)          // 391
#define CVTX_B 6250               // NROWS*WFEAT/8/256  (== 2*HIST_B)
#define CVTW_B 16                 // OUTD*256/8/256
#define HIST_B 3125               // N_EDGES/256
#define TRIPLE_B (3 * HIST_B)     // 9375: striped {cvt,cvt,hist} triples
#define PREP_B (TRIPLE_B + CVTW_B)
#define PS_B (PROJ_TB + NBLK)     // proj + scan_reduce merged

typedef __attribute__((ext_vector_type(8))) short bf16x8;
typedef __attribute__((ext_vector_type(4))) float f32x4;
typedef __attribute__((ext_vector_type(2))) float f32x2;
typedef __attribute__((ext_vector_type(8))) unsigned short ushort8;

#define PRESCALE 2.8853900817779268f   // 2*log2(e)
#define L2E 1.4426950408889634f

static __device__ __forceinline__ unsigned short f2bf(float f) {
    __hip_bfloat16 h = __float2bfloat16(f);
    return *reinterpret_cast<unsigned short*>(&h);
}
static __device__ __forceinline__ float bf_lo(unsigned int w) {
    return __uint_as_float(w << 16);
}
static __device__ __forceinline__ float bf_hi(unsigned int w) {
    return __uint_as_float(w & 0xFFFF0000u);
}
// 2^x via single HW instruction (v_exp_f32)
static __device__ __forceinline__ float exp2_hw(float x) {
    float r;
    asm("v_exp_f32 %0, %1" : "=v"(r) : "v"(x));
    return r;
}
// x + row_ror(x): rotation-add within a 16-lane DPP row (full-rate VALU, no LDS)
template <int CTRL>
static __device__ __forceinline__ float ror_add(float x) {
    int xi = __float_as_int(x);
    int r = __builtin_amdgcn_update_dpp(xi, xi, CTRL, 0xF, 0xF, true);
    return x + __int_as_float(r);
}
// full 16-lane-row sum via ror 8/4/2/1
static __device__ __forceinline__ float row_reduce(float x) {
    x = ror_add<0x128>(x);   // row_ror:8
    x = ror_add<0x124>(x);   // row_ror:4
    x = ror_add<0x122>(x);   // row_ror:2
    x = ror_add<0x121>(x);   // row_ror:1
    return x;
}

// ---------------- prep (NO LDS): striped {cvt,cvt,hist} so the atomic-bound
// hist blocks are co-resident with the BW-bound cvt blocks (overlap, not serial).
__global__ __launch_bounds__(256) void prep_kernel(const float* __restrict__ x,
                                                   unsigned short* __restrict__ xb2,
                                                   unsigned char* __restrict__ xf8,
                                                   const float* __restrict__ fcW,
                                                   unsigned short* __restrict__ fcWb,
                                                   const int* __restrict__ dstp,
                                                   int* __restrict__ deg,
                                                   unsigned short* __restrict__ posin) {
    int bid = blockIdx.x;
    int tid = threadIdx.x;
    if (bid < TRIPLE_B) {
        int q = bid / 3;
        int r = bid - q * 3;
        if (r < 2) {
            // ---- x fp32 [b][node][feat] -> bf16 + fp8 interleaved [node][b][feat]
            int t = (q * 2 + r) * 256 + tid;
            const float4* in4 = (const float4*)x;
            float4 a = in4[2 * t], b = in4[2 * t + 1];
            ushort8 o;
            o[0] = f2bf(a.x); o[1] = f2bf(a.y); o[2] = f2bf(a.z); o[3] = f2bf(a.w);
            o[4] = f2bf(b.x); o[5] = f2bf(b.y); o[6] = f2bf(b.z); o[7] = f2bf(b.w);
            int f0 = t * 8;
            int bb = f0 >= N_NODES * WFEAT;
            int rem = f0 - bb * (N_NODES * WFEAT);
            int node = rem >> 7, feat = rem & 127;
            *reinterpret_cast<ushort8*>(&xb2[(size_t)node * 256 + bb * 128 + feat]) = o;
            // fp8 e4m3 copy for the agg gather path (HW packed convert)
            int w0 = __builtin_amdgcn_cvt_pk_fp8_f32(a.x, a.y, 0, false);
            w0     = __builtin_amdgcn_cvt_pk_fp8_f32(a.z, a.w, w0, true);
            int w1 = __builtin_amdgcn_cvt_pk_fp8_f32(b.x, b.y, 0, false);
            w1     = __builtin_amdgcn_cvt_pk_fp8_f32(b.z, b.w, w1, true);
            uint2 pk; pk.x = (unsigned int)w0; pk.y = (unsigned int)w1;
            *reinterpret_cast<uint2*>(&xf8[(size_t)node * 256 + bb * 128 + feat]) = pk;
        } else {
            // ---- dst-degree histogram; atomic return value = within-node slot (u16)
            int e = q * 256 + tid;
            int d = dstp[e];
            posin[e] = (unsigned short)atomicAdd(&deg[d], 1);
        }
    } else {
        // ---- fcW fp32 -> bf16
        int t = (bid - TRIPLE_B) * 256 + tid;
        const float4* in4 = (const float4*)fcW;
        float4 a = in4[2 * t], b = in4[2 * t + 1];
        ushort8 o;
        o[0] = f2bf(a.x); o[1] = f2bf(a.y); o[2] = f2bf(a.z); o[3] = f2bf(a.w);
        o[4] = f2bf(b.x); o[5] = f2bf(b.y); o[6] = f2bf(b.z); o[7] = f2bf(b.w);
        *reinterpret_cast<ushort8*>(&fcWb[8 * t]) = o;
    }
}

// ---------------- proj via MFMA + scan_reduce, merged by blockIdx range.
// proj: [eq|ek] = emb @ [Wq;Wk]^T, prescaled -> bf16 (blocks 0..PROJ_TB)
// scan_reduce: per-block degree sums (blocks PROJ_TB..PROJ_TB+NBLK)
__global__ __launch_bounds__(256) void proj_scan(const float* __restrict__ emb,
                                                 const float* __restrict__ Wq,
                                                 const float* __restrict__ Wk,
                                                 unsigned short* __restrict__ eqb,
                                                 unsigned short* __restrict__ ekb,
                                                 const int* __restrict__ deg,
                                                 int* __restrict__ bsum) {
    __shared__ unsigned short As[128 * 64];   // 16 KB, swizzled [r][k]
    __shared__ unsigned short Bs[128 * 64];   // 16 KB, swizzled [n][k]
    int tid = threadIdx.x;
    if (blockIdx.x >= PROJ_TB) {
        // ---- scan_reduce branch
        int* sh = (int*)As;
        int i = (blockIdx.x - PROJ_TB) * SCAN_B + tid;
        sh[tid] = (i < N_NODES) ? deg[i] : 0;
        __syncthreads();
        for (int s = SCAN_B / 2; s; s >>= 1) {
            if (tid < s) sh[tid] += sh[tid + s];
            __syncthreads();
        }
        if (tid == 0) bsum[blockIdx.x - PROJ_TB] = sh[0];
        return;
    }
    int wave = tid >> 6, lane = tid & 63;
    int wm = wave >> 1, wn = wave & 1;
    int row0 = blockIdx.x * 128;

#pragma unroll
    for (int c = 0; c < 4; ++c) {
        int idx = (c * 256 + tid) * 8;       // element idx in 128x64 tile
        int r = idx >> 6, k = idx & 63;
        int byte = (r * 128 + k * 2) ^ ((r & 7) << 4);

        int node = row0 + r;
        ushort8 o = {};
        if (node < N_NODES) {
            const float4* p = (const float4*)(emb + (size_t)node * DD + k);
            float4 a = p[0], b = p[1];
            o[0] = f2bf(a.x); o[1] = f2bf(a.y); o[2] = f2bf(a.z); o[3] = f2bf(a.w);
            o[4] = f2bf(b.x); o[5] = f2bf(b.y); o[6] = f2bf(b.z); o[7] = f2bf(b.w);
        }
        *reinterpret_cast<ushort8*>(reinterpret_cast<char*>(As) + byte) = o;

        const float* wsrc = (r < 64) ? (Wq + r * DD + k) : (Wk + (r - 64) * DD + k);
        float4 wa = *(const float4*)wsrc, wb = *((const float4*)wsrc + 1);
        ushort8 ow;
        ow[0] = f2bf(wa.x); ow[1] = f2bf(wa.y); ow[2] = f2bf(wa.z); ow[3] = f2bf(wa.w);
        ow[4] = f2bf(wb.x); ow[5] = f2bf(wb.y); ow[6] = f2bf(wb.z); ow[7] = f2bf(wb.w);
        *reinterpret_cast<ushort8*>(reinterpret_cast<char*>(Bs) + byte) = ow;
    }
    __syncthreads();

    f32x4 acc[4][4] = {};
#pragma unroll
    for (int kk = 0; kk < 2; ++kk) {
        bf16x8 a[4], b[4];
#pragma unroll
        for (int m = 0; m < 4; ++m) {
            int r = wm * 64 + m * 16 + (lane & 15);
            int k = kk * 32 + (lane >> 4) * 8;
            int byte = (r * 128 + k * 2) ^ ((r & 7) << 4);
            a[m] = *reinterpret_cast<bf16x8*>(reinterpret_cast<char*>(As) + byte);
        }
#pragma unroll
        for (int n = 0; n < 4; ++n) {
            int cn = wn * 64 + n * 16 + (lane & 15);
            int k = kk * 32 + (lane >> 4) * 8;
            int byte = (cn * 128 + k * 2) ^ ((cn & 7) << 4);
            b[n] = *reinterpret_cast<bf16x8*>(reinterpret_cast<char*>(Bs) + byte);
        }
#pragma unroll
        for (int m = 0; m < 4; ++m)
#pragma unroll
            for (int n = 0; n < 4; ++n)
                acc[m][n] = __builtin_amdgcn_mfma_f32_16x16x32_bf16(a[m], b[n], acc[m][n], 0, 0, 0);
    }

    // C/D: col = lane&15, row = (lane>>4)*4 + j.  cols 0..63 -> eq, 64..127 -> ek
#pragma unroll
    for (int m = 0; m < 4; ++m) {
#pragma unroll
        for (int n = 0; n < 4; ++n) {
            int col = wn * 64 + n * 16 + (lane & 15);
#pragma unroll
            for (int j = 0; j < 4; ++j) {
                int row = row0 + wm * 64 + m * 16 + (lane >> 4) * 4 + j;
                if (row < N_NODES) {
                    unsigned short val = f2bf(PRESCALE * acc[m][n][j]);
                    if (col < 64) eqb[(size_t)row * DD + col] = val;
                    else          ekb[(size_t)row * DD + col - 64] = val;
                }
            }
        }
    }
}

// each block redundantly scans the raw bsum[] to get its own prefix (no 3rd kernel)
__global__ void scan_final(const int* __restrict__ deg, const int* __restrict__ bsum,
                           int* __restrict__ rowptr) {
    __shared__ int shb[SCAN_B];
    __shared__ int sh[SCAN_B];
    int tid = threadIdx.x;
    int bv = (tid < NBLK) ? bsum[tid] : 0;
    shb[tid] = bv;
    __syncthreads();
    for (int s = 1; s < SCAN_B; s <<= 1) {
        int t = (tid >= s) ? shb[tid - s] : 0;
        __syncthreads();
        shb[tid] += t;
        __syncthreads();
    }
    int myprefix = (blockIdx.x == 0) ? 0 : shb[blockIdx.x - 1];

    int i = blockIdx.x * SCAN_B + tid;
    int v = (i < N_NODES) ? deg[i] : 0;
    sh[tid] = v;
    __syncthreads();
    for (int s = 1; s < SCAN_B; s <<= 1) {
        int t = 0;
        if (tid >= s) t = sh[tid - s];
        __syncthreads();
        sh[tid] += t;
        __syncthreads();
    }
    if (i < N_NODES) {
        int excl = sh[tid] - v + myprefix;
        rowptr[i] = excl;
        if (i == N_NODES - 1) rowptr[N_NODES] = excl + v;
    }
}

// atomic-free scatter, 4 edges/thread with vectorized loads; writes 12 pad zeros
// past N_EDGES so agg's 2-deep idx prefetch needs no clamp.
__global__ void scatter_kernel(const int* __restrict__ src, const int* __restrict__ dst,
                               const int* __restrict__ rowptr,
                               const unsigned short* __restrict__ posin,
                               int* __restrict__ src_sorted) {
    int t = blockIdx.x * blockDim.x + threadIdx.x;
    if (t < 12) src_sorted[N_EDGES + t] = 0;
    int e4 = t * 4;
    if (e4 + 3 < N_EDGES) {
        int4 d4 = *reinterpret_cast<const int4*>(dst + e4);
        ushort4 p4 = *reinterpret_cast<const ushort4*>(posin + e4);
        int4 s4 = *reinterpret_cast<const int4*>(src + e4);
        src_sorted[rowptr[d4.x] + p4.x] = s4.x;
        src_sorted[rowptr[d4.y] + p4.y] = s4.y;
        src_sorted[rowptr[d4.z] + p4.z] = s4.z;
        src_sorted[rowptr[d4.w] + p4.w] = s4.w;
    } else {
        for (int e = e4; e < N_EDGES; ++e)
            src_sorted[rowptr[dst[e]] + posin[e]] = src[e];
    }
}

// ---------------- Fused score + softmax + aggregation, 3-stage pipelined:
// idx prefetch depth-2 (decouples the src_sorted load from the data-gather
// address calc), data prefetch depth-1. One wave per dst node; 4 edges/iter,
// one per 16-lane group (= DPP row). Score via Σv·tanh = Vtot − 2Σv·r with
// DPP row-reduce; agg via fp8 gathers unpacked with v_cvt_pk_f32_fp8.
__global__ __launch_bounds__(256) void agg_fused(const unsigned short* __restrict__ eqb,
                                                 const unsigned short* __restrict__ ekb,
                                                 const float* __restrict__ v,
                                                 const unsigned char* __restrict__ xf8,
                                                 const int* __restrict__ rowptr,
                                                 const int* __restrict__ src_sorted,
                                                 unsigned short* __restrict__ aggb2) {
    int node = (blockIdx.x * 256 + threadIdx.x) >> 6;
    if (node >= N_NODES) return;
    int lane = threadIdx.x & 63;
    int g = lane >> 4, hl = lane & 15;

    uint2 eku = *reinterpret_cast<const uint2*>(ekb + (size_t)node * DD + 4 * hl);
    float k0 = bf_lo(eku.x), k1 = bf_hi(eku.x), k2 = bf_lo(eku.y), k3 = bf_hi(eku.y);
    float4 vv = *reinterpret_cast<const float4*>(v + 4 * hl);
    float vs = row_reduce(vv.x + vv.y + vv.z + vv.w);
    float vtotl2 = vs * L2E;

    int beg = rowptr[node], end = rowptr[node + 1];
    int nIter = (end - beg + 3) >> 2;

    float sum = 0.f;
    f32x2 a0[4] = {}, a1[4] = {};

    // stage-0: idx for iter0+iter1, data for iter0 (src_sorted padded: safe)
    int s_cur = src_sorted[beg + g];
    int s_nxt = src_sorted[beg + 4 + g];
    uint2 equ = *reinterpret_cast<const uint2*>(eqb + (size_t)s_cur * DD + 4 * hl);
    const unsigned char* xr = xf8 + (size_t)s_cur * 256 + 8 * hl;
    uint2 u0 = *reinterpret_cast<const uint2*>(xr);
    uint2 u1 = *reinterpret_cast<const uint2*>(xr + 128);

    for (int i = 0; i < nIter; ++i) {
        bool valid = (beg + 4 * i + g) < end;
        // idx for iter i+2 (2 iterations of latency cover)
        int s_n2 = src_sorted[beg + 4 * (i + 2) + g];
        // data for iter i+1 from the already-resident s_nxt
        uint2 equn = *reinterpret_cast<const uint2*>(eqb + (size_t)s_nxt * DD + 4 * hl);
        const unsigned char* xrn = xf8 + (size_t)s_nxt * 256 + 8 * hl;
        uint2 u0n = *reinterpret_cast<const uint2*>(xrn);
        uint2 u1n = *reinterpret_cast<const uint2*>(xrn + 128);

        float s0 = bf_lo(equ.x) + k0, s1 = bf_hi(equ.x) + k1;
        float s2 = bf_lo(equ.y) + k2, s3 = bf_hi(equ.y) + k3;
        float r =      vv.x * __builtin_amdgcn_rcpf(exp2_hw(s0) + 1.f);
        r = fmaf(vv.y, __builtin_amdgcn_rcpf(exp2_hw(s1) + 1.f), r);
        r = fmaf(vv.z, __builtin_amdgcn_rcpf(exp2_hw(s2) + 1.f), r);
        r = fmaf(vv.w, __builtin_amdgcn_rcpf(exp2_hw(s3) + 1.f), r);
        r = row_reduce(r);
        float w = exp2_hw(fmaf(-2.f * L2E, r, vtotl2));
        w = valid ? w : 0.f;
        sum += w;

        f32x2 p;
        p = __builtin_amdgcn_cvt_pk_f32_fp8((int)u0.x, false); a0[0] += w * p;
        p = __builtin_amdgcn_cvt_pk_f32_fp8((int)u0.x, true);  a0[1] += w * p;
        p = __builtin_amdgcn_cvt_pk_f32_fp8((int)u0.y, false); a0[2] += w * p;
        p = __builtin_amdgcn_cvt_pk_f32_fp8((int)u0.y, true);  a0[3] += w * p;
        p = __builtin_amdgcn_cvt_pk_f32_fp8((int)u1.x, false); a1[0] += w * p;
        p = __builtin_amdgcn_cvt_pk_f32_fp8((int)u1.x, true);  a1[1] += w * p;
        p = __builtin_amdgcn_cvt_pk_f32_fp8((int)u1.y, false); a1[2] += w * p;
        p = __builtin_amdgcn_cvt_pk_f32_fp8((int)u1.y, true);  a1[3] += w * p;

        equ = equn; u0 = u0n; u1 = u1n;
        s_nxt = s_n2;
    }

    // combine the four 16-lane groups
    sum += __shfl_xor(sum, 16); sum += __shfl_xor(sum, 32);
#pragma unroll
    for (int j = 0; j < 4; ++j) {
        a0[j].x += __shfl_xor(a0[j].x, 16); a0[j].x += __shfl_xor(a0[j].x, 32);
        a0[j].y += __shfl_xor(a0[j].y, 16); a0[j].y += __shfl_xor(a0[j].y, 32);
        a1[j].x += __shfl_xor(a1[j].x, 16); a1[j].x += __shfl_xor(a1[j].x, 32);
        a1[j].y += __shfl_xor(a1[j].y, 16); a1[j].y += __shfl_xor(a1[j].y, 32);
    }
    float inv = __builtin_amdgcn_rcpf(sum + 1e-8f);

    if (g < 2) {
        float c0 = (g ? a1[0].x : a0[0].x) * inv, c1 = (g ? a1[0].y : a0[0].y) * inv;
        float c2 = (g ? a1[1].x : a0[1].x) * inv, c3 = (g ? a1[1].y : a0[1].y) * inv;
        float c4 = (g ? a1[2].x : a0[2].x) * inv, c5 = (g ? a1[2].y : a0[2].y) * inv;
        float c6 = (g ? a1[3].x : a0[3].x) * inv, c7 = (g ? a1[3].y : a0[3].y) * inv;
        uint4 o;
        o.x = (unsigned int)f2bf(c0) | ((unsigned int)f2bf(c1) << 16);
        o.y = (unsigned int)f2bf(c2) | ((unsigned int)f2bf(c3) << 16);
        o.z = (unsigned int)f2bf(c4) | ((unsigned int)f2bf(c5) << 16);
        o.w = (unsigned int)f2bf(c6) | ((unsigned int)f2bf(c7) << 16);
        *reinterpret_cast<uint4*>(&aggb2[(size_t)node * 256 + (size_t)g * 128 + 8 * hl]) = o;
    }
}

// ---------------- out = relu([x, agg] @ fcW^T + fcb) via bf16 MFMA
// A rows are batch-major [b*N+node]; xb2/aggb2 are interleaved [node][b][128].
__global__ __launch_bounds__(256) void fc_mfma(const unsigned short* __restrict__ xb2,
                                               const unsigned short* __restrict__ aggb2,
                                               const unsigned short* __restrict__ fcWb,
                                               const float* __restrict__ fcb,
                                               float* __restrict__ out) {
    __shared__ unsigned short As[128 * 64];   // 16 KB, swizzled [r][k]
    __shared__ unsigned short Bs[128 * 64];   // 16 KB, swizzled [n][k]
    int tid = threadIdx.x;
    int wave = tid >> 6, lane = tid & 63;
    int wm = wave >> 1, wn = wave & 1;
    int row0 = blockIdx.x * 128;

    f32x4 acc[4][4] = {};

    for (int ks = 0; ks < 4; ++ks) {
        const unsigned short* Asrc = (ks < 2) ? xb2 : aggb2;
        int kbase = (ks & 1) * 64;
        __syncthreads();
#pragma unroll
        for (int c = 0; c < 4; ++c) {
            int idx = (c * 256 + tid) * 8;       // element idx in 128x64 tile
            int r = idx >> 6, k = idx & 63;
            int row = row0 + r;
            ulonglong2 val = make_ulonglong2(0ull, 0ull);
            if (row < NROWS) {
                int batch = row >= N_NODES;
                int nd = row - (batch ? N_NODES : 0);
                val = *reinterpret_cast<const ulonglong2*>(
                        &Asrc[(size_t)nd * 256 + batch * 128 + kbase + k]);
            }
            int byte = (r * 128 + k * 2) ^ ((r & 7) << 4);
            *reinterpret_cast<ulonglong2*>(reinterpret_cast<char*>(As) + byte) = val;

            ulonglong2 wv = *reinterpret_cast<const ulonglong2*>(&fcWb[(size_t)r * 256 + ks * 64 + k]);
            *reinterpret_cast<ulonglong2*>(reinterpret_cast<char*>(Bs) + byte) = wv;
        }
        __syncthreads();
#pragma unroll
        for (int kk = 0; kk < 2; ++kk) {
            bf16x8 a[4], b[4];
#pragma unroll
            for (int m = 0; m < 4; ++m) {
                int r = wm * 64 + m * 16 + (lane & 15);
                int k = kk * 32 + (lane >> 4) * 8;
                int byte = (r * 128 + k * 2) ^ ((r & 7) << 4);
                a[m] = *reinterpret_cast<bf16x8*>(reinterpret_cast<char*>(As) + byte);
            }
#pragma unroll
            for (int n = 0; n < 4; ++n) {
                int cn = wn * 64 + n * 16 + (lane & 15);
                int k = kk * 32 + (lane >> 4) * 8;
                int byte = (cn * 128 + k * 2) ^ ((cn & 7) << 4);
                b[n] = *reinterpret_cast<bf16x8*>(reinterpret_cast<char*>(Bs) + byte);
            }
#pragma unroll
            for (int m = 0; m < 4; ++m)
#pragma unroll
                for (int n = 0; n < 4; ++n)
                    acc[m][n] = __builtin_amdgcn_mfma_f32_16x16x32_bf16(a[m], b[n], acc[m][n], 0, 0, 0);
        }
    }
    // C/D layout: col = lane&15, row = (lane>>4)*4 + j
#pragma unroll
    for (int m = 0; m < 4; ++m) {
#pragma unroll
        for (int n = 0; n < 4; ++n) {
            int col = wn * 64 + n * 16 + (lane & 15);
            float bias = fcb[col];
#pragma unroll
            for (int j = 0; j < 4; ++j) {
                int row = row0 + wm * 64 + m * 16 + (lane >> 4) * 4 + j;
                if (row < NROWS)
                    out[(size_t)row * OUTD + col] = fmaxf(acc[m][n][j] + bias, 0.f);
            }
        }
    }
}

extern "C" void kernel_launch(void* const* d_in, const int* in_sizes, int n_in,
                              void* d_out, int out_size, void* d_ws, size_t ws_size,
                              hipStream_t stream) {
    const float* x    = (const float*)d_in[0];
    const float* emb  = (const float*)d_in[1];
    const int*   eidx = (const int*)d_in[2];
    const float* Wq   = (const float*)d_in[3];
    const float* Wk   = (const float*)d_in[4];
    const float* v    = (const float*)d_in[5];
    const float* fcW  = (const float*)d_in[6];
    const float* fcb  = (const float*)d_in[7];
    float* out = (float*)d_out;

    char* ws = (char*)d_ws;
    unsigned short* eqb  = (unsigned short*)ws;                  ws += (size_t)N_NODES * DD * 2;
    unsigned short* ekb  = (unsigned short*)ws;                  ws += (size_t)N_NODES * DD * 2;
    unsigned short* xb2  = (unsigned short*)ws;                  ws += (size_t)NROWS * WFEAT * 2;
    unsigned char*  xf8  = (unsigned char*)ws;                   ws += (size_t)NROWS * WFEAT;
    unsigned short* aggb2= (unsigned short*)ws;                  ws += (size_t)NROWS * WFEAT * 2;
    unsigned short* fcWb = (unsigned short*)ws;                  ws += (size_t)OUTD * 256 * 2;
    int* deg        = (int*)ws;                                  ws += (size_t)N_NODES * 4;
    int* rowptr     = (int*)ws;                                  ws += (size_t)(N_NODES + 1) * 4 + 12;
    unsigned short* posin = (unsigned short*)ws;                 ws += (size_t)N_EDGES * 2;
    int* bsum       = (int*)ws;                                  ws += 256 * 4;
    int* src_sorted = (int*)ws;   // N_EDGES + 12 (padded)

    const int* srcp = eidx;
    const int* dstp = eidx + N_EDGES;

    hipMemsetAsync(deg, 0, (size_t)N_NODES * sizeof(int), stream);

    prep_kernel<<<PREP_B, 256, 0, stream>>>(x, xb2, xf8, fcW, fcWb, dstp, deg, posin);
    proj_scan<<<PS_B, 256, 0, stream>>>(emb, Wq, Wk, eqb, ekb, deg, bsum);
    scan_final<<<NBLK, SCAN_B, 0, stream>>>(deg, bsum, rowptr);
    scatter_kernel<<<(N_EDGES / 4 + 255) / 256, 256, 0, stream>>>(srcp, dstp, rowptr, posin,
                                                                  src_sorted);
    agg_fused<<<(N_NODES * 64 + 255) / 256, 256, 0, stream>>>(eqb, ekb, v, xf8, rowptr,
                                                              src_sorted, aggb2);
    fc_mfma<<<(NROWS + 127) / 128, 256, 0, stream>>>(xb2, aggb2, fcWb, fcb, out);
}